// Round 9
// baseline (252.427 us; speedup 1.0000x reference)
//
#include <hip/hip_runtime.h>
#include <hip/hip_bf16.h>

#define D1 256   // node feature dim after concat (DN+DL)
#define DE 128   // trace/edge feature dim
#define KDEG 10  // in/out degree per node
#define NPG 40   // nodes per graph
#define EPG 400  // edges per graph
#define LOG2E 1.44269504088896340736f

typedef __attribute__((ext_vector_type(8))) short short8;   // 8 bf16 (4 VGPRs)
typedef __attribute__((ext_vector_type(4))) float f32x4;

static inline int cdiv(size_t a, int b) { return (int)((a + b - 1) / b); }
static inline size_t al256(size_t x) { return (x + 255) & ~(size_t)255; }

__device__ __forceinline__ short f2b(float x) {
  __hip_bfloat16 h = __float2bfloat16(x);
  return *reinterpret_cast<short*>(&h);
}

__device__ __forceinline__ short8 cvt8(const float* __restrict__ src) {
  float4 v0 = *(const float4*)src;
  float4 v1 = *(const float4*)(src + 4);
  short8 t;
  t[0] = f2b(v0.x); t[1] = f2b(v0.y); t[2] = f2b(v0.z); t[3] = f2b(v0.w);
  t[4] = f2b(v1.x); t[5] = f2b(v1.y); t[6] = f2b(v1.z); t[7] = f2b(v1.w);
  return t;
}

// ---- mega-setup: build bf16 A-operands (Xb concat, xtr_b), bf16 transposed
// weights, merged biases, AND the inverse incidence (cnt pre-zeroed by
// hipMemsetAsync). One launch.
__global__ __launch_bounds__(256) void k_setup(const float* __restrict__ xn,
                                               const float* __restrict__ xlg,
                                               const float* __restrict__ xtr,
                                               const float* __restrict__ Wl1,
                                               const float* __restrict__ Wr1,
                                               const float* __restrict__ We1,
                                               const float* __restrict__ Wl2,
                                               const float* __restrict__ Wr2,
                                               const float* __restrict__ bl1,
                                               const float* __restrict__ br1,
                                               const float* __restrict__ be1,
                                               const float* __restrict__ bl2,
                                               const float* __restrict__ br2,
                                               const int* __restrict__ adj,
                                               int* __restrict__ cnt,
                                               int* __restrict__ inc,
                                               short* __restrict__ Xb,
                                               short* __restrict__ xtr_b,
                                               short* __restrict__ WT12,
                                               short* __restrict__ WTall,
                                               float* __restrict__ blr1,
                                               float* __restrict__ bfull,
                                               int NN, int NE) {
  size_t idx = (size_t)blockIdx.x * 256 + threadIdx.x;
  size_t n;
  n = (size_t)NN * 32;      // Xb concat, 8 bf16 per thread
  if (idx < n) {
    int row = (int)(idx >> 5), q = (int)(idx & 31);
    const float* src = (q < 16) ? &xn[(size_t)row * 128 + q * 8]
                                : &xlg[(size_t)row * 128 + (q - 16) * 8];
    *(short8*)&Xb[(size_t)row * 256 + q * 8] = cvt8(src);
    return;
  }
  idx -= n;
  n = (size_t)NE * 16;      // xtr_b: x_trace -> bf16, 8 per thread
  if (idx < n) {
    *(short8*)&xtr_b[idx * 8] = cvt8(&xtr[idx * 8]);
    return;
  }
  idx -= n;
  n = 512 * 256;            // WT12[n512][k256] from Wl1|Wr1
  if (idx < n) {
    int nn = (int)(idx >> 8), k = (int)(idx & 255);
    float v = (nn < 256) ? Wl1[(size_t)k * 256 + nn] : Wr1[(size_t)k * 256 + (nn - 256)];
    WT12[idx] = f2b(v);
    return;
  }
  idx -= n;
  n = 512 * 128;            // WTall[n512][k128] = We1T(256) | Wl2T(128) | Wr2T(128)
  if (idx < n) {
    int nn = (int)(idx >> 7), k = (int)(idx & 127);
    float v;
    if (nn < 256)      v = We1[(size_t)k * 256 + nn];
    else if (nn < 384) v = Wl2[(size_t)k * 128 + (nn - 256)];
    else               v = Wr2[(size_t)k * 128 + (nn - 384)];
    WTall[idx] = f2b(v);
    return;
  }
  idx -= n;
  n = 512;                  // blr1 = bl1|br1
  if (idx < n) { blr1[idx] = (idx < 256) ? bl1[idx] : br1[idx - 256]; return; }
  idx -= n;
  n = 512;                  // bfull = be1|bl2|br2
  if (idx < n) {
    bfull[idx] = (idx < 256) ? be1[idx] : (idx < 384 ? bl2[idx - 256] : br2[idx - 384]);
    return;
  }
  idx -= n;
  n = (size_t)NE;           // inverse incidence (cnt pre-zeroed by memset)
  if (idx < n) {
    int dst = adj[NE + idx];
    int slot = atomicAdd(&cnt[dst], 1);
    inc[dst * KDEG + slot] = (int)idx;
  }
}

// ---- dual GEMM launch: blocks [0,640) do xlr1 = Xb@WT12 (M=NN,K=256,N=512);
// blocks [640,3840) do pool2 = xtr_b@[Wl2T|Wr2T] (M=NE,K=128,N=256).
__global__ __launch_bounds__(256) void k_gemm_dual(const short* __restrict__ Xb,
                                                   const short* __restrict__ WT12,
                                                   const float* __restrict__ blr1,
                                                   float* __restrict__ xlr1,
                                                   const short* __restrict__ xtr_b,
                                                   const short* __restrict__ WTl2,
                                                   const float* __restrict__ bia2,
                                                   float* __restrict__ pool2,
                                                   int NN, int NE) {
  __shared__ __align__(16) short As[64][40];
  __shared__ __align__(16) short Bs[64][40];
  const int tid = threadIdx.x;
  const int wave = tid >> 6, lane = tid & 63;
  const int quad = lane >> 4, l16 = lane & 15;
  const short *A, *WT;
  const float* bias;
  float* C;
  int K, N, m0, n0;
  {
    int bid = blockIdx.x;
    if (bid < 8 * (NN / 64)) {
      A = Xb; WT = WT12; bias = blr1; C = xlr1; K = 256; N = 512;
      n0 = (bid & 7) * 64; m0 = (bid >> 3) * 64;
    } else {
      bid -= 8 * (NN / 64);
      A = xtr_b; WT = WTl2; bias = bia2; C = pool2; K = 128; N = 256;
      n0 = (bid & 3) * 64; m0 = (bid >> 2) * 64;
    }
  }
  const int wm = (wave & 1) * 32, wn = (wave >> 1) * 32;
  const int r = tid >> 2, kc = (tid & 3) << 3;
  f32x4 acc[2][2] = {};
  short8 pa = *(const short8*)&A[(size_t)(m0 + r) * K + kc];
  short8 pb = *(const short8*)&WT[(size_t)(n0 + r) * K + kc];
  for (int k0 = 0; k0 < K; k0 += 32) {
    *(short8*)&As[r][kc] = pa;
    *(short8*)&Bs[r][kc] = pb;
    __syncthreads();
    if (k0 + 32 < K) {
      pa = *(const short8*)&A[(size_t)(m0 + r) * K + (k0 + 32 + kc)];
      pb = *(const short8*)&WT[(size_t)(n0 + r) * K + (k0 + 32 + kc)];
    }
    short8 af[2], bf[2];
    #pragma unroll
    for (int mt = 0; mt < 2; ++mt)
      af[mt] = *(const short8*)&As[wm + mt * 16 + l16][quad << 3];
    #pragma unroll
    for (int nt = 0; nt < 2; ++nt)
      bf[nt] = *(const short8*)&Bs[wn + nt * 16 + l16][quad << 3];
    #pragma unroll
    for (int mt = 0; mt < 2; ++mt)
      #pragma unroll
      for (int nt = 0; nt < 2; ++nt)
        acc[mt][nt] = __builtin_amdgcn_mfma_f32_16x16x32_bf16(
            af[mt], bf[nt], acc[mt][nt], 0, 0, 0);
    __syncthreads();
  }
  #pragma unroll
  for (int nt = 0; nt < 2; ++nt) {
    int col = n0 + wn + nt * 16 + l16;
    float bs = bias[col];
    #pragma unroll
    for (int mt = 0; mt < 2; ++mt) {
      int row = m0 + wm + mt * 16 + (quad << 2);
      #pragma unroll
      for (int rr = 0; rr < 4; ++rr)
        C[(size_t)(row + rr) * N + col] = acc[mt][nt][rr] + bs;
    }
  }
}

// ---- logit-GEMM over xtr_b: [128 edges]x[128 ea-cols] tile, layer-1 logits
// in the epilogue with per-graph LDS staging. Writes ONLY logit1[NE,4].
__global__ __launch_bounds__(256) void k_logit(const short* __restrict__ A,
                                               const short* __restrict__ WT,
                                               const float* __restrict__ bfull,
                                               const float* __restrict__ att1,
                                               const int* __restrict__ adj,
                                               const float* __restrict__ xlr1,
                                               float* __restrict__ logit1,
                                               int NE) {
  const int K = 128;
  struct SmemGemm { short As[128][40]; short Bs[128][40]; };
  struct SmemEpi  { int sdst[128]; float sxl[14][132]; float sxr[NPG][132]; };
  __shared__ __align__(16) union { SmemGemm g; SmemEpi e; } sm;
  const int tid = threadIdx.x;
  const int wave = tid >> 6, lane = tid & 63;
  const int quad = lane >> 4, l16 = lane & 15;
  int bid = blockIdx.x;
  int l = (bid & 7) * ((int)gridDim.x >> 3) + (bid >> 3);
  const int n0 = (l & 1) << 7;       // 0 or 128 (heads 0-1 / 2-3)
  const int m0 = (l >> 1) << 7;      // edge panel
  const int wm = (wave & 1) * 64, wn = (wave >> 1) * 64;
  const int rr0 = tid >> 2, rr1 = (tid + 256) >> 2;
  const int kc = (tid & 3) << 3;
  f32x4 acc[4][4] = {};
  short8 pa0 = *(const short8*)&A[(size_t)(m0 + rr0) * K + kc];
  short8 pb0 = *(const short8*)&WT[(size_t)(n0 + rr0) * K + kc];
  short8 pa1 = *(const short8*)&A[(size_t)(m0 + rr1) * K + kc];
  short8 pb1 = *(const short8*)&WT[(size_t)(n0 + rr1) * K + kc];
  for (int k0 = 0; k0 < K; k0 += 32) {
    *(short8*)&sm.g.As[rr0][kc] = pa0;
    *(short8*)&sm.g.Bs[rr0][kc] = pb0;
    *(short8*)&sm.g.As[rr1][kc] = pa1;
    *(short8*)&sm.g.Bs[rr1][kc] = pb1;
    __syncthreads();
    if (k0 + 32 < K) {
      pa0 = *(const short8*)&A[(size_t)(m0 + rr0) * K + (k0 + 32 + kc)];
      pb0 = *(const short8*)&WT[(size_t)(n0 + rr0) * K + (k0 + 32 + kc)];
      pa1 = *(const short8*)&A[(size_t)(m0 + rr1) * K + (k0 + 32 + kc)];
      pb1 = *(const short8*)&WT[(size_t)(n0 + rr1) * K + (k0 + 32 + kc)];
    }
    short8 af[4], bf[4];
    #pragma unroll
    for (int mt = 0; mt < 4; ++mt)
      af[mt] = *(const short8*)&sm.g.As[wm + mt * 16 + l16][quad << 3];
    #pragma unroll
    for (int nt = 0; nt < 4; ++nt)
      bf[nt] = *(const short8*)&sm.g.Bs[wn + nt * 16 + l16][quad << 3];
    #pragma unroll
    for (int mt = 0; mt < 4; ++mt)
      #pragma unroll
      for (int nt = 0; nt < 4; ++nt)
        acc[mt][nt] = __builtin_amdgcn_mfma_f32_16x16x32_bf16(
            af[mt], bf[nt], acc[mt][nt], 0, 0, 0);
    __syncthreads();
  }
  // ---- fused layer-1 logit epilogue: per-graph xr staging (40 rows).
  const int gl = m0 / EPG;
  const int gh = (m0 + 127) / EPG;
  const int slo = m0 / KDEG;
  const int nrl = (m0 + 127) / KDEG - slo + 1;  // 13 or 14 xl rows
  if (tid < 128) sm.e.sdst[tid] = adj[NE + m0 + tid];
  for (int s = tid; s < nrl * 128; s += 256) {
    int row = s >> 7, c = s & 127;
    sm.e.sxl[row][c] = xlr1[(size_t)(slo + row) * 512 + n0 + c];
  }
  const int h = (n0 + wn) >> 6;
  float attv[4], bev[4];
  int ccl[4];
  #pragma unroll
  for (int nt = 0; nt < 4; ++nt) {
    int col = n0 + wn + nt * 16 + l16;
    ccl[nt] = col - n0;
    attv[nt] = att1[col] * LOG2E;
    bev[nt] = bfull[col];
  }
  for (int g = gl; g <= gh; ++g) {
    __syncthreads();   // order vs sxl writes (g=gl) / prior reads (g>gl)
    for (int s = tid; s < NPG * 128; s += 256) {
      int row = s >> 7, c = s & 127;
      sm.e.sxr[row][c] = xlr1[(size_t)(g * NPG + row) * 512 + 256 + n0 + c];
    }
    __syncthreads();
    const int elo = g * EPG, ehi = elo + EPG;
    #pragma unroll
    for (int mt = 0; mt < 4; ++mt) {
      #pragma unroll
      for (int r = 0; r < 4; ++r) {
        int le = wm + mt * 16 + (quad << 2) + r;   // 0..127
        int e = m0 + le;
        if (e < elo || e >= ehi) continue;   // uniform across each 16-lane grp
        int srow = e / KDEG - slo;
        int d = sm.e.sdst[le];
        int drow = d - g * NPG;
        float p = 0.f;
        #pragma unroll
        for (int nt = 0; nt < 4; ++nt) {
          float v = acc[mt][nt][r] + bev[nt] + sm.e.sxl[srow][ccl[nt]]
                  + sm.e.sxr[drow][ccl[nt]];
          v = (v > 0.f) ? v : 0.2f * v;
          p += v * attv[nt];
        }
        p += __shfl_xor(p, 1, 64);
        p += __shfl_xor(p, 2, 64);
        p += __shfl_xor(p, 4, 64);
        p += __shfl_xor(p, 8, 64);
        if (l16 == 0) {
          logit1[(size_t)e * 4 + h] = exp2f(p);
        }
      }
    }
  }
}

// ---- fused layer-1 aggregate + nproj row + layer-2 gather/softmax/agg.
// One block per 100-line-edge group; node u = efea[le0] (bijection: each
// node heads exactly one group). Phase1 = agg1 (writes out_node/out_log,
// keeps f32 row in LDS). Phase2 = np = snode @ We2 + be2 (f32, coalesced,
// L2-resident We2). Phase3 = gat2 with in-LDS np (no global nproj).
__global__ __launch_bounds__(256) void k_fused2(const int* __restrict__ adj,
                                                const int* __restrict__ inc,
                                                const int* __restrict__ eadj,
                                                const int* __restrict__ efea,
                                                const float* __restrict__ xlr1,
                                                const float* __restrict__ logit1,
                                                const float* __restrict__ bias1,
                                                const float* __restrict__ pool2,
                                                const float* __restrict__ We2,
                                                const float* __restrict__ be2,
                                                const float* __restrict__ att2,
                                                const float* __restrict__ bias2,
                                                float* __restrict__ out_node,
                                                float* __restrict__ out_log,
                                                float* __restrict__ out_trace,
                                                int NL) {
  int gi = blockIdx.x;
  size_t le0 = (size_t)gi * 100;
  int t = threadIdx.x;
  const int wave = t >> 6, lane = t & 63;
  __shared__ int ein[KDEG], eout[KDEG], nvs;
  __shared__ int se[KDEG], ssrc[KDEG];
  __shared__ float slg[KDEG * 4];
  __shared__ float snode[D1];        // layer-1 output row (f32)
  __shared__ float psum[2][DE];      // nproj partials
  __shared__ float np[DE];           // nproj row
  __shared__ float xs[KDEG][132];    // xl2 rows
  __shared__ float rs[KDEG][132];    // xr2 rows (+np added later)
  __shared__ float as_[DE];          // att2 * log2e
  __shared__ float exs[400];
  __shared__ float rdn[40];
  if (t < KDEG)          ein[t] = eadj[le0 + (size_t)t * KDEG];
  else if (t < 2 * KDEG) eout[t - KDEG] = eadj[(size_t)NL + le0 + (t - KDEG)];
  else if (t == 255)     nvs = efea[le0];
  __syncthreads();
  const int u = nvs;
  if (t < KDEG) se[t] = inc[u * KDEG + t];
  // stage pool2 rows (xl2 of ein; raw xr2 of eout)
  for (int s = t; s < 320; s += 256) {
    int j = s >> 5, q = (s & 31) << 2;
    *(float4*)&xs[j][q] = *(const float4*)&pool2[(size_t)ein[j] * 256 + q];
    *(float4*)&rs[j][q] = *(const float4*)&pool2[(size_t)eout[j] * 256 + 128 + q];
  }
  if (t >= 192 && t < 224) {
    int q = t - 192;
    float4 a4 = *(const float4*)&att2[q << 2];
    float4 o;
    o.x = a4.x * LOG2E; o.y = a4.y * LOG2E;
    o.z = a4.z * LOG2E; o.w = a4.w * LOG2E;
    *(float4*)&as_[q << 2] = o;
  }
  __syncthreads();
  if (t < KDEG) ssrc[t] = adj[se[t]];
  else if (t >= 64 && t < 64 + KDEG * 4) {
    int q = t - 64;
    slg[q] = logit1[(size_t)se[q >> 2] * 4 + (q & 3)];
  }
  __syncthreads();
  // ---- Phase 1: layer-1 aggregate for node u (thread t = channel)
  {
    int h = t >> 6;
    float den = 0.f;
    #pragma unroll
    for (int j = 0; j < KDEG; ++j) den += slg[j * 4 + h];
    float rden = 1.f / (den + 1e-16f);
    float acc = 0.f;
    #pragma unroll
    for (int j = 0; j < KDEG; ++j)
      acc += slg[j * 4 + h] * xlr1[(size_t)ssrc[j] * 512 + t];
    float val = acc * rden + bias1[t];
    snode[t] = val;
    if (t < 128) out_node[(size_t)u * 128 + t] = val;
    else         out_log[(size_t)u * 128 + (t - 128)] = val;
  }
  __syncthreads();
  // ---- Phase 2: np = snode @ We2 + be2 (f32, coalesced We2 reads)
  {
    int c2 = t & 127, kh = t >> 7;
    const float* wb = &We2[(size_t)kh * 128 * 128 + c2];
    float pacc = 0.f;
    #pragma unroll 4
    for (int k = 0; k < 128; ++k)
      pacc += snode[kh * 128 + k] * wb[(size_t)k * 128];
    psum[kh][c2] = pacc;
  }
  __syncthreads();
  if (t < 128) np[t] = psum[0][t] + psum[1][t] + be2[t];
  __syncthreads();
  for (int s = t; s < KDEG * 128; s += 256) {
    int j = s >> 7, c = s & 127;
    rs[j][c] += np[c];
  }
  __syncthreads();
  // ---- Phase 3a: 400 logits; wave w = head w; lane sweeps (j,o) pairs.
  {
    int h = wave;
    const float* aa = &as_[h << 5];
    for (int idx = lane; idx < 100; idx += 64) {
      int j = idx / 10;
      int o = idx - j * 10;
      const float* xa = &xs[j][h << 5];
      const float* ra = &rs[o][h << 5];
      float p = 0.f;
      #pragma unroll
      for (int i = 0; i < 32; i += 4) {
        float4 xv = *(const float4*)&xa[i];
        float4 rv = *(const float4*)&ra[i];
        float4 av = *(const float4*)&aa[i];
        float v;
        v = xv.x + rv.x; v = (v > 0.f) ? v : 0.2f * v; p += v * av.x;
        v = xv.y + rv.y; v = (v > 0.f) ? v : 0.2f * v; p += v * av.y;
        v = xv.z + rv.z; v = (v > 0.f) ? v : 0.2f * v; p += v * av.z;
        v = xv.w + rv.w; v = (v > 0.f) ? v : 0.2f * v; p += v * av.w;
      }
      exs[(j * 10 + o) * 4 + h] = exp2f(p);
    }
  }
  __syncthreads();
  if (t < 40) {       // 1/den per (o,h): h=t&3, o=t>>2
    float d = 0.f;
    #pragma unroll
    for (int j = 0; j < KDEG; ++j) d += exs[(j * 10 + (t >> 2)) * 4 + (t & 3)];
    rdn[t] = 1.f / d;
  }
  __syncthreads();
  // ---- Phase 3b: out[o][c] = (sum_j ex[j,o,h]*xs[j][c])*rdn[o,h] + bias2[c]
  {
    int c = t & 127, h = c >> 5, oh = (t >> 7) * 5;
    float bsv = bias2[c];
    #pragma unroll
    for (int oo = 0; oo < 5; ++oo) {
      int o = oh + oo;
      float acc = 0.f;
      #pragma unroll
      for (int j = 0; j < KDEG; ++j)
        acc += exs[(j * 10 + o) * 4 + h] * xs[j][c];
      out_trace[(size_t)eout[o] * DE + c] = acc * rdn[o * 4 + h] + bsv;
    }
  }
}

extern "C" void kernel_launch(void* const* d_in, const int* in_sizes, int n_in,
                              void* d_out, int out_size, void* d_ws, size_t ws_size,
                              hipStream_t stream) {
  const float* x_node   = (const float*)d_in[0];
  const float* x_trace  = (const float*)d_in[1];
  const float* x_log    = (const float*)d_in[2];
  const int*   node_adj = (const int*)d_in[3];
  const int*   edge_adj = (const int*)d_in[4];
  const int*   edge_efea= (const int*)d_in[5];
  const float* Wl1 = (const float*)d_in[6];
  const float* bl1 = (const float*)d_in[7];
  const float* Wr1 = (const float*)d_in[8];
  const float* br1 = (const float*)d_in[9];
  const float* We1 = (const float*)d_in[10];
  const float* be1 = (const float*)d_in[11];
  const float* att1 = (const float*)d_in[12];
  const float* bias1 = (const float*)d_in[13];
  const float* Wl2 = (const float*)d_in[14];
  const float* bl2 = (const float*)d_in[15];
  const float* Wr2 = (const float*)d_in[16];
  const float* br2 = (const float*)d_in[17];
  const float* We2 = (const float*)d_in[18];
  const float* be2 = (const float*)d_in[19];
  const float* att2 = (const float*)d_in[20];
  const float* bias2 = (const float*)d_in[21];

  const int NN = in_sizes[0] / 128;   // 5120 nodes
  const int NE = in_sizes[1] / 128;   // 51200 edges
  const int NL = in_sizes[5];         // 512000 line edges

  // ---- workspace layout
  char* p = (char*)d_ws;
  float* pool2   = (float*)p; p += al256((size_t)NE * 256 * 4);   // xl2|xr2
  float* xlr1    = (float*)p; p += al256((size_t)NN * 512 * 4);
  short* Xb      = (short*)p; p += al256((size_t)NN * D1 * 2);
  short* xtr_b   = (short*)p; p += al256((size_t)NE * DE * 2);
  float* logit1  = (float*)p; p += al256((size_t)NE * 4 * 4);
  int*   inc     = (int*)p;   p += al256((size_t)NN * KDEG * 4);
  int*   cnt     = (int*)p;   p += al256((size_t)NN * 4);
  short* WT12    = (short*)p; p += al256((size_t)512 * 256 * 2);
  short* WTall   = (short*)p; p += al256((size_t)512 * 128 * 2);
  float* blr1    = (float*)p; p += al256(512 * 4);
  float* bfull   = (float*)p; p += al256(512 * 4);
  (void)ws_size;

  float* out_node  = (float*)d_out;
  float* out_trace = out_node + (size_t)NN * 128;
  float* out_log   = out_trace + (size_t)NE * 128;

  // ---- zero slot counters, then setup (+incidence) in one launch
  hipMemsetAsync(cnt, 0, (size_t)NN * 4, stream);
  {
    size_t total = (size_t)NN * 32 + (size_t)NE * 16 +
                   512 * 256 + 512 * 128 + 512 + 512 + (size_t)NE;
    k_setup<<<cdiv(total, 256), 256, 0, stream>>>(x_node, x_log, x_trace,
                                                  Wl1, Wr1, We1, Wl2, Wr2,
                                                  bl1, br1, be1, bl2, br2,
                                                  node_adj, cnt, inc,
                                                  Xb, xtr_b,
                                                  WT12, WTall, blr1, bfull,
                                                  NN, NE);
  }

  // ---- dual GEMM: xlr1 (640 blocks) + pool2 streamer (3200 blocks)
  k_gemm_dual<<<8 * (NN / 64) + 4 * (NE / 64), 256, 0, stream>>>(
      Xb, WT12, blr1, xlr1,
      xtr_b, WTall + (size_t)256 * 128, bfull + 256, pool2, NN, NE);

  // ---- layer-1 logits: dedicated GEMM+epilogue kernel (800 uniform blocks)
  k_logit<<<2 * (NE / 128), 256, 0, stream>>>(xtr_b, WTall, bfull, att1,
                                              node_adj, xlr1, logit1, NE);

  // ---- fused agg1 + nproj + gat2 (one block per node/group)
  k_fused2<<<NN, 256, 0, stream>>>(node_adj, inc, edge_adj, edge_efea,
                                   xlr1, logit1, bias1, pool2, We2, be2,
                                   att2, bias2, out_node, out_log, out_trace,
                                   NL);
}

// Round 10
// 219.745 us; speedup vs baseline: 1.1487x; 1.1487x over previous
//
#include <hip/hip_runtime.h>
#include <hip/hip_bf16.h>

#define D1 256   // node feature dim after concat (DN+DL)
#define DE 128   // trace/edge feature dim
#define KDEG 10  // in/out degree per node
#define NPG 40   // nodes per graph
#define EPG 400  // edges per graph
#define LOG2E 1.44269504088896340736f

typedef __attribute__((ext_vector_type(8))) short short8;   // 8 bf16 (4 VGPRs)
typedef __attribute__((ext_vector_type(4))) float f32x4;

static inline int cdiv(size_t a, int b) { return (int)((a + b - 1) / b); }
static inline size_t al256(size_t x) { return (x + 255) & ~(size_t)255; }

__device__ __forceinline__ short f2b(float x) {
  __hip_bfloat16 h = __float2bfloat16(x);
  return *reinterpret_cast<short*>(&h);
}

__device__ __forceinline__ short8 cvt8(const float* __restrict__ src) {
  float4 v0 = *(const float4*)src;
  float4 v1 = *(const float4*)(src + 4);
  short8 t;
  t[0] = f2b(v0.x); t[1] = f2b(v0.y); t[2] = f2b(v0.z); t[3] = f2b(v0.w);
  t[4] = f2b(v1.x); t[5] = f2b(v1.y); t[6] = f2b(v1.z); t[7] = f2b(v1.w);
  return t;
}

// ---- mega-setup: build bf16 A-operands (Xb concat, xtr_b), bf16 transposed
// weights, merged biases, AND the inverse incidence (cnt pre-zeroed by
// hipMemsetAsync). One launch.
__global__ __launch_bounds__(256) void k_setup(const float* __restrict__ xn,
                                               const float* __restrict__ xlg,
                                               const float* __restrict__ xtr,
                                               const float* __restrict__ Wl1,
                                               const float* __restrict__ Wr1,
                                               const float* __restrict__ We1,
                                               const float* __restrict__ Wl2,
                                               const float* __restrict__ Wr2,
                                               const float* __restrict__ We2,
                                               const float* __restrict__ bl1,
                                               const float* __restrict__ br1,
                                               const float* __restrict__ be1,
                                               const float* __restrict__ bl2,
                                               const float* __restrict__ br2,
                                               const int* __restrict__ adj,
                                               int* __restrict__ cnt,
                                               int* __restrict__ inc,
                                               short* __restrict__ Xb,
                                               short* __restrict__ xtr_b,
                                               short* __restrict__ WT12,
                                               short* __restrict__ WTall,
                                               short* __restrict__ We2T,
                                               float* __restrict__ blr1,
                                               float* __restrict__ bfull,
                                               int NN, int NE) {
  size_t idx = (size_t)blockIdx.x * 256 + threadIdx.x;
  size_t n;
  n = (size_t)NN * 32;      // Xb concat, 8 bf16 per thread
  if (idx < n) {
    int row = (int)(idx >> 5), q = (int)(idx & 31);
    const float* src = (q < 16) ? &xn[(size_t)row * 128 + q * 8]
                                : &xlg[(size_t)row * 128 + (q - 16) * 8];
    *(short8*)&Xb[(size_t)row * 256 + q * 8] = cvt8(src);
    return;
  }
  idx -= n;
  n = (size_t)NE * 16;      // xtr_b: x_trace -> bf16, 8 per thread
  if (idx < n) {
    *(short8*)&xtr_b[idx * 8] = cvt8(&xtr[idx * 8]);
    return;
  }
  idx -= n;
  n = 512 * 256;            // WT12[n512][k256] from Wl1|Wr1
  if (idx < n) {
    int nn = (int)(idx >> 8), k = (int)(idx & 255);
    float v = (nn < 256) ? Wl1[(size_t)k * 256 + nn] : Wr1[(size_t)k * 256 + (nn - 256)];
    WT12[idx] = f2b(v);
    return;
  }
  idx -= n;
  n = 512 * 128;            // WTall[n512][k128] = We1T(256) | Wl2T(128) | Wr2T(128)
  if (idx < n) {
    int nn = (int)(idx >> 7), k = (int)(idx & 127);
    float v;
    if (nn < 256)      v = We1[(size_t)k * 256 + nn];
    else if (nn < 384) v = Wl2[(size_t)k * 128 + (nn - 256)];
    else               v = Wr2[(size_t)k * 128 + (nn - 384)];
    WTall[idx] = f2b(v);
    return;
  }
  idx -= n;
  n = 128 * 256;            // We2T[n128][k256]
  if (idx < n) {
    int nn = (int)(idx >> 8), k = (int)(idx & 255);
    We2T[idx] = f2b(We2[(size_t)k * 128 + nn]);
    return;
  }
  idx -= n;
  n = 512;                  // blr1 = bl1|br1
  if (idx < n) { blr1[idx] = (idx < 256) ? bl1[idx] : br1[idx - 256]; return; }
  idx -= n;
  n = 512;                  // bfull = be1|bl2|br2
  if (idx < n) {
    bfull[idx] = (idx < 256) ? be1[idx] : (idx < 384 ? bl2[idx - 256] : br2[idx - 384]);
    return;
  }
  idx -= n;
  n = (size_t)NE;           // inverse incidence (cnt pre-zeroed by memset)
  if (idx < n) {
    int dst = adj[NE + idx];
    int slot = atomicAdd(&cnt[dst], 1);
    inc[dst * KDEG + slot] = (int)idx;
  }
}

// ---- dual GEMM launch: blocks [0,640) do xlr1 = Xb@WT12 (M=NN,K=256,N=512);
// blocks [640,3840) do pool2 = xtr_b@[Wl2T|Wr2T] (M=NE,K=128,N=256).
__global__ __launch_bounds__(256) void k_gemm_dual(const short* __restrict__ Xb,
                                                   const short* __restrict__ WT12,
                                                   const float* __restrict__ blr1,
                                                   float* __restrict__ xlr1,
                                                   const short* __restrict__ xtr_b,
                                                   const short* __restrict__ WTl2,
                                                   const float* __restrict__ bia2,
                                                   float* __restrict__ pool2,
                                                   int NN, int NE) {
  __shared__ __align__(16) short As[64][40];
  __shared__ __align__(16) short Bs[64][40];
  const int tid = threadIdx.x;
  const int wave = tid >> 6, lane = tid & 63;
  const int quad = lane >> 4, l16 = lane & 15;
  const short *A, *WT;
  const float* bias;
  float* C;
  int K, N, m0, n0;
  {
    int bid = blockIdx.x;
    if (bid < 8 * (NN / 64)) {
      A = Xb; WT = WT12; bias = blr1; C = xlr1; K = 256; N = 512;
      n0 = (bid & 7) * 64; m0 = (bid >> 3) * 64;
    } else {
      bid -= 8 * (NN / 64);
      A = xtr_b; WT = WTl2; bias = bia2; C = pool2; K = 128; N = 256;
      n0 = (bid & 3) * 64; m0 = (bid >> 2) * 64;
    }
  }
  const int wm = (wave & 1) * 32, wn = (wave >> 1) * 32;
  const int r = tid >> 2, kc = (tid & 3) << 3;
  f32x4 acc[2][2] = {};
  short8 pa = *(const short8*)&A[(size_t)(m0 + r) * K + kc];
  short8 pb = *(const short8*)&WT[(size_t)(n0 + r) * K + kc];
  for (int k0 = 0; k0 < K; k0 += 32) {
    *(short8*)&As[r][kc] = pa;
    *(short8*)&Bs[r][kc] = pb;
    __syncthreads();
    if (k0 + 32 < K) {
      pa = *(const short8*)&A[(size_t)(m0 + r) * K + (k0 + 32 + kc)];
      pb = *(const short8*)&WT[(size_t)(n0 + r) * K + (k0 + 32 + kc)];
    }
    short8 af[2], bf[2];
    #pragma unroll
    for (int mt = 0; mt < 2; ++mt)
      af[mt] = *(const short8*)&As[wm + mt * 16 + l16][quad << 3];
    #pragma unroll
    for (int nt = 0; nt < 2; ++nt)
      bf[nt] = *(const short8*)&Bs[wn + nt * 16 + l16][quad << 3];
    #pragma unroll
    for (int mt = 0; mt < 2; ++mt)
      #pragma unroll
      for (int nt = 0; nt < 2; ++nt)
        acc[mt][nt] = __builtin_amdgcn_mfma_f32_16x16x32_bf16(
            af[mt], bf[nt], acc[mt][nt], 0, 0, 0);
    __syncthreads();
  }
  #pragma unroll
  for (int nt = 0; nt < 2; ++nt) {
    int col = n0 + wn + nt * 16 + l16;
    float bs = bias[col];
    #pragma unroll
    for (int mt = 0; mt < 2; ++mt) {
      int row = m0 + wm + mt * 16 + (quad << 2);
      #pragma unroll
      for (int rr = 0; rr < 2 * 2; ++rr)
        if (rr < 4) C[(size_t)(row + rr) * N + col] = acc[mt][nt][rr] + bs;
    }
  }
}

// ---- MFMA GEMM 64x64 tile (nproj): C = A(bf16)[M,K] @ WT(bf16 [N,K]) + bias
__global__ __launch_bounds__(256) void k_gemm_mfma64(const short* __restrict__ A,
                                                     const short* __restrict__ WT,
                                                     const float* __restrict__ bias,
                                                     float* __restrict__ C,
                                                     int M, int K, int N) {
  __shared__ __align__(16) short As[64][40];
  __shared__ __align__(16) short Bs[64][40];
  const int tid = threadIdx.x;
  const int wave = tid >> 6, lane = tid & 63;
  const int quad = lane >> 4, l16 = lane & 15;
  const int m0 = blockIdx.y * 64, n0 = blockIdx.x * 64;
  const int wm = (wave & 1) * 32, wn = (wave >> 1) * 32;
  const int r = tid >> 2, kc = (tid & 3) << 3;
  f32x4 acc[2][2] = {};
  short8 pa = *(const short8*)&A[(size_t)(m0 + r) * K + kc];
  short8 pb = *(const short8*)&WT[(size_t)(n0 + r) * K + kc];
  for (int k0 = 0; k0 < K; k0 += 32) {
    *(short8*)&As[r][kc] = pa;
    *(short8*)&Bs[r][kc] = pb;
    __syncthreads();
    if (k0 + 32 < K) {
      pa = *(const short8*)&A[(size_t)(m0 + r) * K + (k0 + 32 + kc)];
      pb = *(const short8*)&WT[(size_t)(n0 + r) * K + (k0 + 32 + kc)];
    }
    short8 af[2], bf[2];
    #pragma unroll
    for (int mt = 0; mt < 2; ++mt)
      af[mt] = *(const short8*)&As[wm + mt * 16 + l16][quad << 3];
    #pragma unroll
    for (int nt = 0; nt < 2; ++nt)
      bf[nt] = *(const short8*)&Bs[wn + nt * 16 + l16][quad << 3];
    #pragma unroll
    for (int mt = 0; mt < 2; ++mt)
      #pragma unroll
      for (int nt = 0; nt < 2; ++nt)
        acc[mt][nt] = __builtin_amdgcn_mfma_f32_16x16x32_bf16(
            af[mt], bf[nt], acc[mt][nt], 0, 0, 0);
    __syncthreads();
  }
  #pragma unroll
  for (int nt = 0; nt < 2; ++nt) {
    int col = n0 + wn + nt * 16 + l16;
    float bs = bias[col];
    #pragma unroll
    for (int mt = 0; mt < 2; ++mt) {
      int row = m0 + wm + mt * 16 + (quad << 2);
      #pragma unroll
      for (int rr = 0; rr < 4; ++rr)
        C[(size_t)(row + rr) * N + col] = acc[mt][nt][rr] + bs;
    }
  }
}

// ---- logit-GEMM, 128x64 tile = ONE HEAD per block (1600 uniform blocks).
// acc[2][4] halves VGPR vs the 128x128 tile -> ~2x occupancy. Epilogue
// stages only the head's 64 cols of xl/xr. Writes ONLY logit1[NE,4].
__global__ __launch_bounds__(256) void k_logit(const short* __restrict__ A,
                                               const short* __restrict__ WT,
                                               const float* __restrict__ bfull,
                                               const float* __restrict__ att1,
                                               const int* __restrict__ adj,
                                               const float* __restrict__ xlr1,
                                               float* __restrict__ logit1,
                                               int NE) {
  const int K = 128;
  struct SmemGemm { short As[128][40]; short Bs[64][40]; };
  struct SmemEpi  { int sdst[128]; float sxl[14][68]; float sxr[NPG][68]; };
  __shared__ __align__(16) union { SmemGemm g; SmemEpi e; } sm;
  const int tid = threadIdx.x;
  const int wave = tid >> 6, lane = tid & 63;
  const int quad = lane >> 4, l16 = lane & 15;
  int bid = blockIdx.x;
  int l = (bid & 7) * ((int)gridDim.x >> 3) + (bid >> 3);
  const int n0 = (l & 3) << 6;       // 0,64,128,192 -> head = n0>>6
  const int m0 = (l >> 2) << 7;      // edge panel (128 edges)
  const int wm = wave * 32;          // wave covers 32 rows x 64 cols
  const int ra0 = tid >> 2, ra1 = ra0 + 64;   // A rows (2 per thread); B row = ra0
  const int kc = (tid & 3) << 3;
  f32x4 acc[2][4] = {};
  short8 pa0 = *(const short8*)&A[(size_t)(m0 + ra0) * K + kc];
  short8 pa1 = *(const short8*)&A[(size_t)(m0 + ra1) * K + kc];
  short8 pb  = *(const short8*)&WT[(size_t)(n0 + ra0) * K + kc];
  for (int k0 = 0; k0 < K; k0 += 32) {
    *(short8*)&sm.g.As[ra0][kc] = pa0;
    *(short8*)&sm.g.As[ra1][kc] = pa1;
    *(short8*)&sm.g.Bs[ra0][kc] = pb;
    __syncthreads();
    if (k0 + 32 < K) {
      pa0 = *(const short8*)&A[(size_t)(m0 + ra0) * K + (k0 + 32 + kc)];
      pa1 = *(const short8*)&A[(size_t)(m0 + ra1) * K + (k0 + 32 + kc)];
      pb  = *(const short8*)&WT[(size_t)(n0 + ra0) * K + (k0 + 32 + kc)];
    }
    short8 af[2], bf[4];
    #pragma unroll
    for (int mt = 0; mt < 2; ++mt)
      af[mt] = *(const short8*)&sm.g.As[wm + mt * 16 + l16][quad << 3];
    #pragma unroll
    for (int nt = 0; nt < 4; ++nt)
      bf[nt] = *(const short8*)&sm.g.Bs[nt * 16 + l16][quad << 3];
    #pragma unroll
    for (int mt = 0; mt < 2; ++mt)
      #pragma unroll
      for (int nt = 0; nt < 4; ++nt)
        acc[mt][nt] = __builtin_amdgcn_mfma_f32_16x16x32_bf16(
            af[mt], bf[nt], acc[mt][nt], 0, 0, 0);
    __syncthreads();
  }
  // ---- fused layer-1 logit epilogue: per-graph xr staging (40 rows x 64 cols)
  const int gl = m0 / EPG;
  const int gh = (m0 + 127) / EPG;
  const int slo = m0 / KDEG;
  const int nrl = (m0 + 127) / KDEG - slo + 1;  // 13 or 14 xl rows
  if (tid < 128) sm.e.sdst[tid] = adj[NE + m0 + tid];
  for (int s = tid; s < nrl * 64; s += 256) {
    int row = s >> 6, c = s & 63;
    sm.e.sxl[row][c] = xlr1[(size_t)(slo + row) * 512 + n0 + c];
  }
  const int h = n0 >> 6;
  float attv[4], bev[4];
  int ccl[4];
  #pragma unroll
  for (int nt = 0; nt < 4; ++nt) {
    int col = n0 + nt * 16 + l16;
    ccl[nt] = col - n0;
    attv[nt] = att1[col] * LOG2E;
    bev[nt] = bfull[col];
  }
  for (int g = gl; g <= gh; ++g) {
    __syncthreads();   // order vs sxl writes (g=gl) / prior reads (g>gl)
    for (int s = tid; s < NPG * 64; s += 256) {
      int row = s >> 6, c = s & 63;
      sm.e.sxr[row][c] = xlr1[(size_t)(g * NPG + row) * 512 + 256 + n0 + c];
    }
    __syncthreads();
    const int elo = g * EPG, ehi = elo + EPG;
    #pragma unroll
    for (int mt = 0; mt < 2; ++mt) {
      #pragma unroll
      for (int r = 0; r < 4; ++r) {
        int le = wm + mt * 16 + (quad << 2) + r;   // 0..127
        int e = m0 + le;
        if (e < elo || e >= ehi) continue;   // uniform across each 16-lane grp
        int srow = e / KDEG - slo;
        int d = sm.e.sdst[le];
        int drow = d - g * NPG;
        float p = 0.f;
        #pragma unroll
        for (int nt = 0; nt < 4; ++nt) {
          float v = acc[mt][nt][r] + bev[nt] + sm.e.sxl[srow][ccl[nt]]
                  + sm.e.sxr[drow][ccl[nt]];
          v = (v > 0.f) ? v : 0.2f * v;
          p += v * attv[nt];
        }
        p += __shfl_xor(p, 1, 64);
        p += __shfl_xor(p, 2, 64);
        p += __shfl_xor(p, 4, 64);
        p += __shfl_xor(p, 8, 64);
        if (l16 == 0) {
          logit1[(size_t)e * 4 + h] = exp2f(p);
        }
      }
    }
  }
}

// ---- layer1 aggregate (gather) + in-block den + fused fp32 output writes
__global__ __launch_bounds__(256) void k_agg1(const int* __restrict__ adj,
                                              const int* __restrict__ inc,
                                              const float* __restrict__ xlr1,
                                              const float* __restrict__ logit1,
                                              const float* __restrict__ bias1,
                                              short* __restrict__ nodeoutb,
                                              float* __restrict__ out_node,
                                              float* __restrict__ out_log) {
  int u = blockIdx.x, c = threadIdx.x;
  __shared__ int se[KDEG], ssrc[KDEG];
  __shared__ float slg[KDEG * 4];
  if (c < KDEG) se[c] = inc[u * KDEG + c];
  __syncthreads();
  if (c < KDEG) ssrc[c] = adj[se[c]];
  else if (c >= 64 && c < 64 + KDEG * 4) {
    int t = c - 64;
    slg[t] = logit1[(size_t)se[t >> 2] * 4 + (t & 3)];
  }
  __syncthreads();
  int h = c >> 6;
  float den = 0.f;
  #pragma unroll
  for (int j = 0; j < KDEG; ++j) den += slg[j * 4 + h];
  float rden = 1.f / (den + 1e-16f);
  float acc = 0.f;
  #pragma unroll
  for (int j = 0; j < KDEG; ++j)
    acc += slg[j * 4 + h] * xlr1[(size_t)ssrc[j] * 512 + c];
  float val = acc * rden + bias1[c];
  nodeoutb[(size_t)u * D1 + c] = f2b(val);
  if (c < 128) out_node[(size_t)u * 128 + c] = val;
  else         out_log[(size_t)u * 128 + (c - 128)] = val;
}

// ---- layer2 gather: one block per 100-line-edge group (node).
// Reads xl2|xr2 from pool2 [NE,256]; writes final out_trace (single write).
// Phase A mapped wave==head -> conflict-free LDS reads.
__global__ __launch_bounds__(256) void k_gat2_v4(const int* __restrict__ eadj,
                                                 const int* __restrict__ efea,
                                                 const float* __restrict__ pool2,
                                                 const float* __restrict__ nproj,
                                                 const float* __restrict__ att2,
                                                 const float* __restrict__ bias2,
                                                 float* __restrict__ out_trace,
                                                 int NL) {
  int gi = blockIdx.x;
  size_t le0 = (size_t)gi * 100;
  int t = threadIdx.x;
  const int wave = t >> 6, lane = t & 63;
  __shared__ int ein[KDEG], eout[KDEG], nvs;
  __shared__ float xs[KDEG][132];    // xl2 rows (pad 132: conflict-spread)
  __shared__ float rs[KDEG][132];    // xr2 rows + nproj
  __shared__ float as_[DE];          // att2 * log2e
  __shared__ float exs[400];         // ex[(j*10+o)*4+h]
  __shared__ float rdn[40];          // 1/den [o*4+h]
  if (t < KDEG)          ein[t] = eadj[le0 + (size_t)t * KDEG];
  else if (t < 2 * KDEG) eout[t - KDEG] = eadj[(size_t)NL + le0 + (t - KDEG)];
  else if (t == 255)     nvs = efea[le0];
  __syncthreads();
  int nv = nvs;
  for (int s = t; s < 320; s += 256) {
    int j = s >> 5, q = (s & 31) << 2;
    *(float4*)&xs[j][q] = *(const float4*)&pool2[(size_t)ein[j] * 256 + q];
    float4 tr4 = *(const float4*)&pool2[(size_t)eout[j] * 256 + 128 + q];
    float4 ea4 = *(const float4*)&nproj[(size_t)nv * DE + q];
    float4 r;
    r.x = tr4.x + ea4.x; r.y = tr4.y + ea4.y;
    r.z = tr4.z + ea4.z; r.w = tr4.w + ea4.w;
    *(float4*)&rs[j][q] = r;
  }
  if (t < 32) {
    float4 a4 = *(const float4*)&att2[t << 2];
    float4 o;
    o.x = a4.x * LOG2E; o.y = a4.y * LOG2E;
    o.z = a4.z * LOG2E; o.w = a4.w * LOG2E;
    *(float4*)&as_[t << 2] = o;
  }
  __syncthreads();
  // Phase A: 400 logits; wave w handles head w; lane sweeps (j,o) pairs.
  {
    int h = wave;
    const float* aa = &as_[h << 5];
    for (int idx = lane; idx < 100; idx += 64) {
      int j = idx / 10;
      int o = idx - j * 10;
      const float* xa = &xs[j][h << 5];
      const float* ra = &rs[o][h << 5];
      float p = 0.f;
      #pragma unroll
      for (int i = 0; i < 32; i += 4) {
        float4 xv = *(const float4*)&xa[i];
        float4 rv = *(const float4*)&ra[i];
        float4 av = *(const float4*)&aa[i];
        float v;
        v = xv.x + rv.x; v = (v > 0.f) ? v : 0.2f * v; p += v * av.x;
        v = xv.y + rv.y; v = (v > 0.f) ? v : 0.2f * v; p += v * av.y;
        v = xv.z + rv.z; v = (v > 0.f) ? v : 0.2f * v; p += v * av.z;
        v = xv.w + rv.w; v = (v > 0.f) ? v : 0.2f * v; p += v * av.w;
      }
      exs[(j * 10 + o) * 4 + h] = exp2f(p);
    }
  }
  __syncthreads();
  if (t < 40) {       // 1/den per (o,h): h=t&3, o=t>>2
    float d = 0.f;
    #pragma unroll
    for (int j = 0; j < KDEG; ++j) d += exs[(j * 10 + (t >> 2)) * 4 + (t & 3)];
    rdn[t] = 1.f / d;
  }
  __syncthreads();
  // Phase B: out[o][c] = (sum_j ex[j,o,h] * xl[j][c]) * rden[o,h] + bias[c]
  {
    int c = t & 127, h = c >> 5, oh = (t >> 7) * 5;
    float bsv = bias2[c];
    #pragma unroll
    for (int oo = 0; oo < 5; ++oo) {
      int o = oh + oo;
      float acc = 0.f;
      #pragma unroll
      for (int j = 0; j < KDEG; ++j)
        acc += exs[(j * 10 + o) * 4 + h] * xs[j][c];
      out_trace[(size_t)eout[o] * DE + c] = acc * rdn[o * 4 + h] + bsv;
    }
  }
}

extern "C" void kernel_launch(void* const* d_in, const int* in_sizes, int n_in,
                              void* d_out, int out_size, void* d_ws, size_t ws_size,
                              hipStream_t stream) {
  const float* x_node   = (const float*)d_in[0];
  const float* x_trace  = (const float*)d_in[1];
  const float* x_log    = (const float*)d_in[2];
  const int*   node_adj = (const int*)d_in[3];
  const int*   edge_adj = (const int*)d_in[4];
  const int*   edge_efea= (const int*)d_in[5];
  const float* Wl1 = (const float*)d_in[6];
  const float* bl1 = (const float*)d_in[7];
  const float* Wr1 = (const float*)d_in[8];
  const float* br1 = (const float*)d_in[9];
  const float* We1 = (const float*)d_in[10];
  const float* be1 = (const float*)d_in[11];
  const float* att1 = (const float*)d_in[12];
  const float* bias1 = (const float*)d_in[13];
  const float* Wl2 = (const float*)d_in[14];
  const float* bl2 = (const float*)d_in[15];
  const float* Wr2 = (const float*)d_in[16];
  const float* br2 = (const float*)d_in[17];
  const float* We2 = (const float*)d_in[18];
  const float* be2 = (const float*)d_in[19];
  const float* att2 = (const float*)d_in[20];
  const float* bias2 = (const float*)d_in[21];

  const int NN = in_sizes[0] / 128;   // 5120 nodes
  const int NE = in_sizes[1] / 128;   // 51200 edges
  const int NL = in_sizes[5];         // 512000 line edges

  // ---- workspace layout
  char* p = (char*)d_ws;
  float* pool2   = (float*)p; p += al256((size_t)NE * 256 * 4);   // xl2|xr2
  float* xlr1    = (float*)p; p += al256((size_t)NN * 512 * 4);
  short* Xb      = (short*)p; p += al256((size_t)NN * D1 * 2);
  short* xtr_b   = (short*)p; p += al256((size_t)NE * DE * 2);
  short* nodeoutb= (short*)p; p += al256((size_t)NN * D1 * 2);
  float* nproj   = (float*)p; p += al256((size_t)NN * DE * 4);
  float* logit1  = (float*)p; p += al256((size_t)NE * 4 * 4);
  int*   inc     = (int*)p;   p += al256((size_t)NN * KDEG * 4);
  int*   cnt     = (int*)p;   p += al256((size_t)NN * 4);
  short* WT12    = (short*)p; p += al256((size_t)512 * 256 * 2);
  short* WTall   = (short*)p; p += al256((size_t)512 * 128 * 2);
  short* We2T    = (short*)p; p += al256((size_t)128 * 256 * 2);
  float* blr1    = (float*)p; p += al256(512 * 4);
  float* bfull   = (float*)p; p += al256(512 * 4);
  (void)ws_size;

  float* out_node  = (float*)d_out;
  float* out_trace = out_node + (size_t)NN * 128;
  float* out_log   = out_trace + (size_t)NE * 128;

  // ---- zero slot counters, then setup (+incidence) in one launch
  hipMemsetAsync(cnt, 0, (size_t)NN * 4, stream);
  {
    size_t total = (size_t)NN * 32 + (size_t)NE * 16 +
                   512 * 256 + 512 * 128 + 128 * 256 + 512 + 512 + (size_t)NE;
    k_setup<<<cdiv(total, 256), 256, 0, stream>>>(x_node, x_log, x_trace,
                                                  Wl1, Wr1, We1, Wl2, Wr2, We2,
                                                  bl1, br1, be1, bl2, br2,
                                                  node_adj, cnt, inc,
                                                  Xb, xtr_b,
                                                  WT12, WTall, We2T, blr1, bfull,
                                                  NN, NE);
  }

  // ---- dual GEMM: xlr1 (640 blocks) + pool2 streamer (3200 blocks)
  k_gemm_dual<<<8 * (NN / 64) + 4 * (NE / 64), 256, 0, stream>>>(
      Xb, WT12, blr1, xlr1,
      xtr_b, WTall + (size_t)256 * 128, bfull + 256, pool2, NN, NE);

  // ---- layer-1 logits: one head per block, 1600 uniform blocks
  k_logit<<<4 * (NE / 128), 256, 0, stream>>>(xtr_b, WTall, bfull, att1,
                                              node_adj, xlr1, logit1, NE);

  // ---- layer 1 aggregate (in-block den; writes nodeoutb + node/log outputs)
  k_agg1<<<NN, 256, 0, stream>>>(node_adj, inc, xlr1, logit1, bias1,
                                 nodeoutb, out_node, out_log);

  // ---- layer 2: node projection GEMM
  k_gemm_mfma64<<<dim3(DE / 64, NN / 64), 256, 0, stream>>>(nodeoutb, We2T, be2,
                                                            nproj, NN, D1, DE);

  // ---- layer 2: fused gather/softmax/aggregate
  k_gat2_v4<<<NN, 256, 0, stream>>>(edge_adj, edge_efea, pool2, nproj,
                                    att2, bias2, out_trace, NL);
}

// Round 11
// 216.987 us; speedup vs baseline: 1.1633x; 1.0127x over previous
//
#include <hip/hip_runtime.h>
#include <hip/hip_bf16.h>

#define D1 256   // node feature dim after concat (DN+DL)
#define DE 128   // trace/edge feature dim
#define KDEG 10  // in/out degree per node
#define NPG 40   // nodes per graph
#define EPG 400  // edges per graph
#define LOG2E 1.44269504088896340736f

typedef __attribute__((ext_vector_type(8))) short short8;   // 8 bf16 (4 VGPRs)
typedef __attribute__((ext_vector_type(4))) float f32x4;

static inline int cdiv(size_t a, int b) { return (int)((a + b - 1) / b); }
static inline size_t al256(size_t x) { return (x + 255) & ~(size_t)255; }

__device__ __forceinline__ short f2b(float x) {
  __hip_bfloat16 h = __float2bfloat16(x);
  return *reinterpret_cast<short*>(&h);
}

__device__ __forceinline__ short8 cvt8(const float* __restrict__ src) {
  float4 v0 = *(const float4*)src;
  float4 v1 = *(const float4*)(src + 4);
  short8 t;
  t[0] = f2b(v0.x); t[1] = f2b(v0.y); t[2] = f2b(v0.z); t[3] = f2b(v0.w);
  t[4] = f2b(v1.x); t[5] = f2b(v1.y); t[6] = f2b(v1.z); t[7] = f2b(v1.w);
  return t;
}

// ---- mega-setup: build bf16 A-operands (Xb concat, xtr_b), bf16 transposed
// weights, merged biases, AND the inverse incidence (cnt pre-zeroed by
// hipMemsetAsync). One launch.
__global__ __launch_bounds__(256) void k_setup(const float* __restrict__ xn,
                                               const float* __restrict__ xlg,
                                               const float* __restrict__ xtr,
                                               const float* __restrict__ Wl1,
                                               const float* __restrict__ Wr1,
                                               const float* __restrict__ We1,
                                               const float* __restrict__ Wl2,
                                               const float* __restrict__ Wr2,
                                               const float* __restrict__ We2,
                                               const float* __restrict__ bl1,
                                               const float* __restrict__ br1,
                                               const float* __restrict__ be1,
                                               const float* __restrict__ bl2,
                                               const float* __restrict__ br2,
                                               const int* __restrict__ adj,
                                               int* __restrict__ cnt,
                                               int* __restrict__ inc,
                                               short* __restrict__ Xb,
                                               short* __restrict__ xtr_b,
                                               short* __restrict__ WT12,
                                               short* __restrict__ WTall,
                                               short* __restrict__ We2T,
                                               float* __restrict__ blr1,
                                               float* __restrict__ bfull,
                                               int NN, int NE) {
  size_t idx = (size_t)blockIdx.x * 256 + threadIdx.x;
  size_t n;
  n = (size_t)NN * 32;      // Xb concat, 8 bf16 per thread
  if (idx < n) {
    int row = (int)(idx >> 5), q = (int)(idx & 31);
    const float* src = (q < 16) ? &xn[(size_t)row * 128 + q * 8]
                                : &xlg[(size_t)row * 128 + (q - 16) * 8];
    *(short8*)&Xb[(size_t)row * 256 + q * 8] = cvt8(src);
    return;
  }
  idx -= n;
  n = (size_t)NE * 16;      // xtr_b: x_trace -> bf16, 8 per thread
  if (idx < n) {
    *(short8*)&xtr_b[idx * 8] = cvt8(&xtr[idx * 8]);
    return;
  }
  idx -= n;
  n = 512 * 256;            // WT12[n512][k256] from Wl1|Wr1
  if (idx < n) {
    int nn = (int)(idx >> 8), k = (int)(idx & 255);
    float v = (nn < 256) ? Wl1[(size_t)k * 256 + nn] : Wr1[(size_t)k * 256 + (nn - 256)];
    WT12[idx] = f2b(v);
    return;
  }
  idx -= n;
  n = 512 * 128;            // WTall[n512][k128] = We1T(256) | Wl2T(128) | Wr2T(128)
  if (idx < n) {
    int nn = (int)(idx >> 7), k = (int)(idx & 127);
    float v;
    if (nn < 256)      v = We1[(size_t)k * 256 + nn];
    else if (nn < 384) v = Wl2[(size_t)k * 128 + (nn - 256)];
    else               v = Wr2[(size_t)k * 128 + (nn - 384)];
    WTall[idx] = f2b(v);
    return;
  }
  idx -= n;
  n = 128 * 256;            // We2T[n128][k256]
  if (idx < n) {
    int nn = (int)(idx >> 8), k = (int)(idx & 255);
    We2T[idx] = f2b(We2[(size_t)k * 128 + nn]);
    return;
  }
  idx -= n;
  n = 512;                  // blr1 = bl1|br1
  if (idx < n) { blr1[idx] = (idx < 256) ? bl1[idx] : br1[idx - 256]; return; }
  idx -= n;
  n = 512;                  // bfull = be1|bl2|br2
  if (idx < n) {
    bfull[idx] = (idx < 256) ? be1[idx] : (idx < 384 ? bl2[idx - 256] : br2[idx - 384]);
    return;
  }
  idx -= n;
  n = (size_t)NE;           // inverse incidence (cnt pre-zeroed by memset)
  if (idx < n) {
    int dst = adj[NE + idx];
    int slot = atomicAdd(&cnt[dst], 1);
    inc[dst * KDEG + slot] = (int)idx;
  }
}

// ---- dual GEMM launch: blocks [0,640) do xlr1 = Xb@WT12 (M=NN,K=256,N=512);
// blocks [640,3840) do pool2 = xtr_b@[Wl2T|Wr2T] (M=NE,K=128,N=256).
__global__ __launch_bounds__(256) void k_gemm_dual(const short* __restrict__ Xb,
                                                   const short* __restrict__ WT12,
                                                   const float* __restrict__ blr1,
                                                   float* __restrict__ xlr1,
                                                   const short* __restrict__ xtr_b,
                                                   const short* __restrict__ WTl2,
                                                   const float* __restrict__ bia2,
                                                   float* __restrict__ pool2,
                                                   int NN, int NE) {
  __shared__ __align__(16) short As[64][40];
  __shared__ __align__(16) short Bs[64][40];
  const int tid = threadIdx.x;
  const int wave = tid >> 6, lane = tid & 63;
  const int quad = lane >> 4, l16 = lane & 15;
  const short *A, *WT;
  const float* bias;
  float* C;
  int K, N, m0, n0;
  {
    int bid = blockIdx.x;
    if (bid < 8 * (NN / 64)) {
      A = Xb; WT = WT12; bias = blr1; C = xlr1; K = 256; N = 512;
      n0 = (bid & 7) * 64; m0 = (bid >> 3) * 64;
    } else {
      bid -= 8 * (NN / 64);
      A = xtr_b; WT = WTl2; bias = bia2; C = pool2; K = 128; N = 256;
      n0 = (bid & 3) * 64; m0 = (bid >> 2) * 64;
    }
  }
  const int wm = (wave & 1) * 32, wn = (wave >> 1) * 32;
  const int r = tid >> 2, kc = (tid & 3) << 3;
  f32x4 acc[2][2] = {};
  short8 pa = *(const short8*)&A[(size_t)(m0 + r) * K + kc];
  short8 pb = *(const short8*)&WT[(size_t)(n0 + r) * K + kc];
  for (int k0 = 0; k0 < K; k0 += 32) {
    *(short8*)&As[r][kc] = pa;
    *(short8*)&Bs[r][kc] = pb;
    __syncthreads();
    if (k0 + 32 < K) {
      pa = *(const short8*)&A[(size_t)(m0 + r) * K + (k0 + 32 + kc)];
      pb = *(const short8*)&WT[(size_t)(n0 + r) * K + (k0 + 32 + kc)];
    }
    short8 af[2], bf[2];
    #pragma unroll
    for (int mt = 0; mt < 2; ++mt)
      af[mt] = *(const short8*)&As[wm + mt * 16 + l16][quad << 3];
    #pragma unroll
    for (int nt = 0; nt < 2; ++nt)
      bf[nt] = *(const short8*)&Bs[wn + nt * 16 + l16][quad << 3];
    #pragma unroll
    for (int mt = 0; mt < 2; ++mt)
      #pragma unroll
      for (int nt = 0; nt < 2; ++nt)
        acc[mt][nt] = __builtin_amdgcn_mfma_f32_16x16x32_bf16(
            af[mt], bf[nt], acc[mt][nt], 0, 0, 0);
    __syncthreads();
  }
  #pragma unroll
  for (int nt = 0; nt < 2; ++nt) {
    int col = n0 + wn + nt * 16 + l16;
    float bs = bias[col];
    #pragma unroll
    for (int mt = 0; mt < 2; ++mt) {
      int row = m0 + wm + mt * 16 + (quad << 2);
      #pragma unroll
      for (int rr = 0; rr < 4; ++rr)
        C[(size_t)(row + rr) * N + col] = acc[mt][nt][rr] + bs;
    }
  }
}

// ---- MFMA GEMM 64x64 tile, BK=64 (nproj only; K multiple of 64).
// Half the K-steps/barriers of the BK=32 version -> less fixed latency
// for this small 160-block launch.
__global__ __launch_bounds__(256) void k_gemm_mfma64(const short* __restrict__ A,
                                                     const short* __restrict__ WT,
                                                     const float* __restrict__ bias,
                                                     float* __restrict__ C,
                                                     int M, int K, int N) {
  __shared__ __align__(16) short As[64][72];
  __shared__ __align__(16) short Bs[64][72];
  const int tid = threadIdx.x;
  const int wave = tid >> 6, lane = tid & 63;
  const int quad = lane >> 4, l16 = lane & 15;
  const int m0 = blockIdx.y * 64, n0 = blockIdx.x * 64;
  const int wm = (wave & 1) * 32, wn = (wave >> 1) * 32;
  const int r = tid >> 2, kc = (tid & 3) << 4;   // 16 bf16 per thread per mat
  f32x4 acc[2][2] = {};
  short8 pa0 = *(const short8*)&A[(size_t)(m0 + r) * K + kc];
  short8 pa1 = *(const short8*)&A[(size_t)(m0 + r) * K + kc + 8];
  short8 pb0 = *(const short8*)&WT[(size_t)(n0 + r) * K + kc];
  short8 pb1 = *(const short8*)&WT[(size_t)(n0 + r) * K + kc + 8];
  for (int k0 = 0; k0 < K; k0 += 64) {
    *(short8*)&As[r][kc] = pa0;
    *(short8*)&As[r][kc + 8] = pa1;
    *(short8*)&Bs[r][kc] = pb0;
    *(short8*)&Bs[r][kc + 8] = pb1;
    __syncthreads();
    if (k0 + 64 < K) {
      pa0 = *(const short8*)&A[(size_t)(m0 + r) * K + (k0 + 64 + kc)];
      pa1 = *(const short8*)&A[(size_t)(m0 + r) * K + (k0 + 64 + kc + 8)];
      pb0 = *(const short8*)&WT[(size_t)(n0 + r) * K + (k0 + 64 + kc)];
      pb1 = *(const short8*)&WT[(size_t)(n0 + r) * K + (k0 + 64 + kc + 8)];
    }
    #pragma unroll
    for (int kk = 0; kk < 2; ++kk) {
      short8 af[2], bf[2];
      #pragma unroll
      for (int mt = 0; mt < 2; ++mt)
        af[mt] = *(const short8*)&As[wm + mt * 16 + l16][kk * 32 + (quad << 3)];
      #pragma unroll
      for (int nt = 0; nt < 2; ++nt)
        bf[nt] = *(const short8*)&Bs[wn + nt * 16 + l16][kk * 32 + (quad << 3)];
      #pragma unroll
      for (int mt = 0; mt < 2; ++mt)
        #pragma unroll
        for (int nt = 0; nt < 2; ++nt)
          acc[mt][nt] = __builtin_amdgcn_mfma_f32_16x16x32_bf16(
              af[mt], bf[nt], acc[mt][nt], 0, 0, 0);
    }
    __syncthreads();
  }
  #pragma unroll
  for (int nt = 0; nt < 2; ++nt) {
    int col = n0 + wn + nt * 16 + l16;
    float bs = bias[col];
    #pragma unroll
    for (int mt = 0; mt < 2; ++mt) {
      int row = m0 + wm + mt * 16 + (quad << 2);
      #pragma unroll
      for (int rr = 0; rr < 4; ++rr)
        C[(size_t)(row + rr) * N + col] = acc[mt][nt][rr] + bs;
    }
  }
}

// ---- logit-GEMM, 128x64 tile = ONE HEAD per block (1600 uniform blocks).
__global__ __launch_bounds__(256) void k_logit(const short* __restrict__ A,
                                               const short* __restrict__ WT,
                                               const float* __restrict__ bfull,
                                               const float* __restrict__ att1,
                                               const int* __restrict__ adj,
                                               const float* __restrict__ xlr1,
                                               float* __restrict__ logit1,
                                               int NE) {
  const int K = 128;
  struct SmemGemm { short As[128][40]; short Bs[64][40]; };
  struct SmemEpi  { int sdst[128]; float sxl[14][68]; float sxr[NPG][68]; };
  __shared__ __align__(16) union { SmemGemm g; SmemEpi e; } sm;
  const int tid = threadIdx.x;
  const int wave = tid >> 6, lane = tid & 63;
  const int quad = lane >> 4, l16 = lane & 15;
  int bid = blockIdx.x;
  int l = (bid & 7) * ((int)gridDim.x >> 3) + (bid >> 3);
  const int n0 = (l & 3) << 6;       // 0,64,128,192 -> head = n0>>6
  const int m0 = (l >> 2) << 7;      // edge panel (128 edges)
  const int wm = wave * 32;          // wave covers 32 rows x 64 cols
  const int ra0 = tid >> 2, ra1 = ra0 + 64;   // A rows (2 per thread); B row = ra0
  const int kc = (tid & 3) << 3;
  f32x4 acc[2][4] = {};
  short8 pa0 = *(const short8*)&A[(size_t)(m0 + ra0) * K + kc];
  short8 pa1 = *(const short8*)&A[(size_t)(m0 + ra1) * K + kc];
  short8 pb  = *(const short8*)&WT[(size_t)(n0 + ra0) * K + kc];
  for (int k0 = 0; k0 < K; k0 += 32) {
    *(short8*)&sm.g.As[ra0][kc] = pa0;
    *(short8*)&sm.g.As[ra1][kc] = pa1;
    *(short8*)&sm.g.Bs[ra0][kc] = pb;
    __syncthreads();
    if (k0 + 32 < K) {
      pa0 = *(const short8*)&A[(size_t)(m0 + ra0) * K + (k0 + 32 + kc)];
      pa1 = *(const short8*)&A[(size_t)(m0 + ra1) * K + (k0 + 32 + kc)];
      pb  = *(const short8*)&WT[(size_t)(n0 + ra0) * K + (k0 + 32 + kc)];
    }
    short8 af[2], bf[4];
    #pragma unroll
    for (int mt = 0; mt < 2; ++mt)
      af[mt] = *(const short8*)&sm.g.As[wm + mt * 16 + l16][quad << 3];
    #pragma unroll
    for (int nt = 0; nt < 4; ++nt)
      bf[nt] = *(const short8*)&sm.g.Bs[nt * 16 + l16][quad << 3];
    #pragma unroll
    for (int mt = 0; mt < 2; ++mt)
      #pragma unroll
      for (int nt = 0; nt < 4; ++nt)
        acc[mt][nt] = __builtin_amdgcn_mfma_f32_16x16x32_bf16(
            af[mt], bf[nt], acc[mt][nt], 0, 0, 0);
    __syncthreads();
  }
  // ---- fused layer-1 logit epilogue: per-graph xr staging (40 rows x 64 cols)
  const int gl = m0 / EPG;
  const int gh = (m0 + 127) / EPG;
  const int slo = m0 / KDEG;
  const int nrl = (m0 + 127) / KDEG - slo + 1;  // 13 or 14 xl rows
  if (tid < 128) sm.e.sdst[tid] = adj[NE + m0 + tid];
  for (int s = tid; s < nrl * 64; s += 256) {
    int row = s >> 6, c = s & 63;
    sm.e.sxl[row][c] = xlr1[(size_t)(slo + row) * 512 + n0 + c];
  }
  const int h = n0 >> 6;
  float attv[4], bev[4];
  int ccl[4];
  #pragma unroll
  for (int nt = 0; nt < 4; ++nt) {
    int col = n0 + nt * 16 + l16;
    ccl[nt] = col - n0;
    attv[nt] = att1[col] * LOG2E;
    bev[nt] = bfull[col];
  }
  for (int g = gl; g <= gh; ++g) {
    __syncthreads();   // order vs sxl writes (g=gl) / prior reads (g>gl)
    for (int s = tid; s < NPG * 64; s += 256) {
      int row = s >> 6, c = s & 63;
      sm.e.sxr[row][c] = xlr1[(size_t)(g * NPG + row) * 512 + 256 + n0 + c];
    }
    __syncthreads();
    const int elo = g * EPG, ehi = elo + EPG;
    #pragma unroll
    for (int mt = 0; mt < 2; ++mt) {
      #pragma unroll
      for (int r = 0; r < 4; ++r) {
        int le = wm + mt * 16 + (quad << 2) + r;   // 0..127
        int e = m0 + le;
        if (e < elo || e >= ehi) continue;   // uniform across each 16-lane grp
        int srow = e / KDEG - slo;
        int d = sm.e.sdst[le];
        int drow = d - g * NPG;
        float p = 0.f;
        #pragma unroll
        for (int nt = 0; nt < 4; ++nt) {
          float v = acc[mt][nt][r] + bev[nt] + sm.e.sxl[srow][ccl[nt]]
                  + sm.e.sxr[drow][ccl[nt]];
          v = (v > 0.f) ? v : 0.2f * v;
          p += v * attv[nt];
        }
        p += __shfl_xor(p, 1, 64);
        p += __shfl_xor(p, 2, 64);
        p += __shfl_xor(p, 4, 64);
        p += __shfl_xor(p, 8, 64);
        if (l16 == 0) {
          logit1[(size_t)e * 4 + h] = exp2f(p);
        }
      }
    }
  }
}

// ---- layer1 aggregate (gather) + in-block den + fused fp32 output writes.
// XCD-chunked block->node swizzle: node u's block reads xlr1 rows u-10..u-1
// (each row shared by 10 consecutive nodes) -> contiguous node ranges per
// XCD make the sliding window L2-resident (T1).
__global__ __launch_bounds__(256) void k_agg1(const int* __restrict__ adj,
                                              const int* __restrict__ inc,
                                              const float* __restrict__ xlr1,
                                              const float* __restrict__ logit1,
                                              const float* __restrict__ bias1,
                                              short* __restrict__ nodeoutb,
                                              float* __restrict__ out_node,
                                              float* __restrict__ out_log) {
  int u = (blockIdx.x & 7) * ((int)gridDim.x >> 3) + (blockIdx.x >> 3);
  int c = threadIdx.x;
  __shared__ int se[KDEG], ssrc[KDEG];
  __shared__ float slg[KDEG * 4];
  if (c < KDEG) se[c] = inc[u * KDEG + c];
  __syncthreads();
  if (c < KDEG) ssrc[c] = adj[se[c]];
  else if (c >= 64 && c < 64 + KDEG * 4) {
    int t = c - 64;
    slg[t] = logit1[(size_t)se[t >> 2] * 4 + (t & 3)];
  }
  __syncthreads();
  int h = c >> 6;
  float den = 0.f;
  #pragma unroll
  for (int j = 0; j < KDEG; ++j) den += slg[j * 4 + h];
  float rden = 1.f / (den + 1e-16f);
  float acc = 0.f;
  #pragma unroll
  for (int j = 0; j < KDEG; ++j)
    acc += slg[j * 4 + h] * xlr1[(size_t)ssrc[j] * 512 + c];
  float val = acc * rden + bias1[c];
  nodeoutb[(size_t)u * D1 + c] = f2b(val);
  if (c < 128) out_node[(size_t)u * 128 + c] = val;
  else         out_log[(size_t)u * 128 + (c - 128)] = val;
}

// ---- layer2 gather: one block per 100-line-edge group (node).
// Reads xl2|xr2 from pool2 [NE,256]; writes final out_trace (single write).
// Phase A mapped wave==head -> conflict-free LDS reads.
__global__ __launch_bounds__(256) void k_gat2_v4(const int* __restrict__ eadj,
                                                 const int* __restrict__ efea,
                                                 const float* __restrict__ pool2,
                                                 const float* __restrict__ nproj,
                                                 const float* __restrict__ att2,
                                                 const float* __restrict__ bias2,
                                                 float* __restrict__ out_trace,
                                                 int NL) {
  int gi = blockIdx.x;
  size_t le0 = (size_t)gi * 100;
  int t = threadIdx.x;
  const int wave = t >> 6, lane = t & 63;
  __shared__ int ein[KDEG], eout[KDEG], nvs;
  __shared__ float xs[KDEG][132];    // xl2 rows (pad 132: conflict-spread)
  __shared__ float rs[KDEG][132];    // xr2 rows + nproj
  __shared__ float as_[DE];          // att2 * log2e
  __shared__ float exs[400];         // ex[(j*10+o)*4+h]
  __shared__ float rdn[40];          // 1/den [o*4+h]
  if (t < KDEG)          ein[t] = eadj[le0 + (size_t)t * KDEG];
  else if (t < 2 * KDEG) eout[t - KDEG] = eadj[(size_t)NL + le0 + (t - KDEG)];
  else if (t == 255)     nvs = efea[le0];
  __syncthreads();
  int nv = nvs;
  for (int s = t; s < 320; s += 256) {
    int j = s >> 5, q = (s & 31) << 2;
    *(float4*)&xs[j][q] = *(const float4*)&pool2[(size_t)ein[j] * 256 + q];
    float4 tr4 = *(const float4*)&pool2[(size_t)eout[j] * 256 + 128 + q];
    float4 ea4 = *(const float4*)&nproj[(size_t)nv * DE + q];
    float4 r;
    r.x = tr4.x + ea4.x; r.y = tr4.y + ea4.y;
    r.z = tr4.z + ea4.z; r.w = tr4.w + ea4.w;
    *(float4*)&rs[j][q] = r;
  }
  if (t < 32) {
    float4 a4 = *(const float4*)&att2[t << 2];
    float4 o;
    o.x = a4.x * LOG2E; o.y = a4.y * LOG2E;
    o.z = a4.z * LOG2E; o.w = a4.w * LOG2E;
    *(float4*)&as_[t << 2] = o;
  }
  __syncthreads();
  // Phase A: 400 logits; wave w handles head w; lane sweeps (j,o) pairs.
  {
    int h = wave;
    const float* aa = &as_[h << 5];
    for (int idx = lane; idx < 100; idx += 64) {
      int j = idx / 10;
      int o = idx - j * 10;
      const float* xa = &xs[j][h << 5];
      const float* ra = &rs[o][h << 5];
      float p = 0.f;
      #pragma unroll
      for (int i = 0; i < 32; i += 4) {
        float4 xv = *(const float4*)&xa[i];
        float4 rv = *(const float4*)&ra[i];
        float4 av = *(const float4*)&aa[i];
        float v;
        v = xv.x + rv.x; v = (v > 0.f) ? v : 0.2f * v; p += v * av.x;
        v = xv.y + rv.y; v = (v > 0.f) ? v : 0.2f * v; p += v * av.y;
        v = xv.z + rv.z; v = (v > 0.f) ? v : 0.2f * v; p += v * av.z;
        v = xv.w + rv.w; v = (v > 0.f) ? v : 0.2f * v; p += v * av.w;
      }
      exs[(j * 10 + o) * 4 + h] = exp2f(p);
    }
  }
  __syncthreads();
  if (t < 40) {       // 1/den per (o,h): h=t&3, o=t>>2
    float d = 0.f;
    #pragma unroll
    for (int j = 0; j < KDEG; ++j) d += exs[(j * 10 + (t >> 2)) * 4 + (t & 3)];
    rdn[t] = 1.f / d;
  }
  __syncthreads();
  // Phase B: out[o][c] = (sum_j ex[j,o,h] * xl[j][c]) * rden[o,h] + bias[c]
  {
    int c = t & 127, h = c >> 5, oh = (t >> 7) * 5;
    float bsv = bias2[c];
    #pragma unroll
    for (int oo = 0; oo < 5; ++oo) {
      int o = oh + oo;
      float acc = 0.f;
      #pragma unroll
      for (int j = 0; j < KDEG; ++j)
        acc += exs[(j * 10 + o) * 4 + h] * xs[j][c];
      out_trace[(size_t)eout[o] * DE + c] = acc * rdn[o * 4 + h] + bsv;
    }
  }
}

extern "C" void kernel_launch(void* const* d_in, const int* in_sizes, int n_in,
                              void* d_out, int out_size, void* d_ws, size_t ws_size,
                              hipStream_t stream) {
  const float* x_node   = (const float*)d_in[0];
  const float* x_trace  = (const float*)d_in[1];
  const float* x_log    = (const float*)d_in[2];
  const int*   node_adj = (const int*)d_in[3];
  const int*   edge_adj = (const int*)d_in[4];
  const int*   edge_efea= (const int*)d_in[5];
  const float* Wl1 = (const float*)d_in[6];
  const float* bl1 = (const float*)d_in[7];
  const float* Wr1 = (const float*)d_in[8];
  const float* br1 = (const float*)d_in[9];
  const float* We1 = (const float*)d_in[10];
  const float* be1 = (const float*)d_in[11];
  const float* att1 = (const float*)d_in[12];
  const float* bias1 = (const float*)d_in[13];
  const float* Wl2 = (const float*)d_in[14];
  const float* bl2 = (const float*)d_in[15];
  const float* Wr2 = (const float*)d_in[16];
  const float* br2 = (const float*)d_in[17];
  const float* We2 = (const float*)d_in[18];
  const float* be2 = (const float*)d_in[19];
  const float* att2 = (const float*)d_in[20];
  const float* bias2 = (const float*)d_in[21];

  const int NN = in_sizes[0] / 128;   // 5120 nodes
  const int NE = in_sizes[1] / 128;   // 51200 edges
  const int NL = in_sizes[5];         // 512000 line edges

  // ---- workspace layout
  char* p = (char*)d_ws;
  float* pool2   = (float*)p; p += al256((size_t)NE * 256 * 4);   // xl2|xr2
  float* xlr1    = (float*)p; p += al256((size_t)NN * 512 * 4);
  short* Xb      = (short*)p; p += al256((size_t)NN * D1 * 2);
  short* xtr_b   = (short*)p; p += al256((size_t)NE * DE * 2);
  short* nodeoutb= (short*)p; p += al256((size_t)NN * D1 * 2);
  float* nproj   = (float*)p; p += al256((size_t)NN * DE * 4);
  float* logit1  = (float*)p; p += al256((size_t)NE * 4 * 4);
  int*   inc     = (int*)p;   p += al256((size_t)NN * KDEG * 4);
  int*   cnt     = (int*)p;   p += al256((size_t)NN * 4);
  short* WT12    = (short*)p; p += al256((size_t)512 * 256 * 2);
  short* WTall   = (short*)p; p += al256((size_t)512 * 128 * 2);
  short* We2T    = (short*)p; p += al256((size_t)128 * 256 * 2);
  float* blr1    = (float*)p; p += al256(512 * 4);
  float* bfull   = (float*)p; p += al256(512 * 4);
  (void)ws_size;

  float* out_node  = (float*)d_out;
  float* out_trace = out_node + (size_t)NN * 128;
  float* out_log   = out_trace + (size_t)NE * 128;

  // ---- zero slot counters, then setup (+incidence) in one launch
  hipMemsetAsync(cnt, 0, (size_t)NN * 4, stream);
  {
    size_t total = (size_t)NN * 32 + (size_t)NE * 16 +
                   512 * 256 + 512 * 128 + 128 * 256 + 512 + 512 + (size_t)NE;
    k_setup<<<cdiv(total, 256), 256, 0, stream>>>(x_node, x_log, x_trace,
                                                  Wl1, Wr1, We1, Wl2, Wr2, We2,
                                                  bl1, br1, be1, bl2, br2,
                                                  node_adj, cnt, inc,
                                                  Xb, xtr_b,
                                                  WT12, WTall, We2T, blr1, bfull,
                                                  NN, NE);
  }

  // ---- dual GEMM: xlr1 (640 blocks) + pool2 streamer (3200 blocks)
  k_gemm_dual<<<8 * (NN / 64) + 4 * (NE / 64), 256, 0, stream>>>(
      Xb, WT12, blr1, xlr1,
      xtr_b, WTall + (size_t)256 * 128, bfull + 256, pool2, NN, NE);

  // ---- layer-1 logits: one head per block, 1600 uniform blocks
  k_logit<<<4 * (NE / 128), 256, 0, stream>>>(xtr_b, WTall, bfull, att1,
                                              node_adj, xlr1, logit1, NE);

  // ---- layer 1 aggregate (XCD-swizzled; writes nodeoutb + node/log outputs)
  k_agg1<<<NN, 256, 0, stream>>>(node_adj, inc, xlr1, logit1, bias1,
                                 nodeoutb, out_node, out_log);

  // ---- layer 2: node projection GEMM (BK=64)
  k_gemm_mfma64<<<dim3(DE / 64, NN / 64), 256, 0, stream>>>(nodeoutb, We2T, be2,
                                                            nproj, NN, D1, DE);

  // ---- layer 2: fused gather/softmax/aggregate
  k_gat2_v4<<<NN, 256, 0, stream>>>(edge_adj, edge_efea, pool2, nproj,
                                    att2, bias2, out_trace, NL);
}

// Round 12
// 212.761 us; speedup vs baseline: 1.1864x; 1.0199x over previous
//
#include <hip/hip_runtime.h>
#include <hip/hip_bf16.h>

#define D1 256   // node feature dim after concat (DN+DL)
#define DE 128   // trace/edge feature dim
#define KDEG 10  // in/out degree per node
#define NPG 40   // nodes per graph
#define EPG 400  // edges per graph
#define LOG2E 1.44269504088896340736f

typedef __attribute__((ext_vector_type(8))) short short8;   // 8 bf16 (4 VGPRs)
typedef __attribute__((ext_vector_type(4))) float f32x4;

static inline int cdiv(size_t a, int b) { return (int)((a + b - 1) / b); }
static inline size_t al256(size_t x) { return (x + 255) & ~(size_t)255; }

__device__ __forceinline__ short f2b(float x) {
  __hip_bfloat16 h = __float2bfloat16(x);
  return *reinterpret_cast<short*>(&h);
}

__device__ __forceinline__ short8 cvt8(const float* __restrict__ src) {
  float4 v0 = *(const float4*)src;
  float4 v1 = *(const float4*)(src + 4);
  short8 t;
  t[0] = f2b(v0.x); t[1] = f2b(v0.y); t[2] = f2b(v0.z); t[3] = f2b(v0.w);
  t[4] = f2b(v1.x); t[5] = f2b(v1.y); t[6] = f2b(v1.z); t[7] = f2b(v1.w);
  return t;
}

// ---- mega-setup: build bf16 A-operands (Xb concat, xtr_b), bf16 transposed
// weights, merged biases, AND the inverse incidence (cnt pre-zeroed by
// hipMemsetAsync). One launch.
__global__ __launch_bounds__(256) void k_setup(const float* __restrict__ xn,
                                               const float* __restrict__ xlg,
                                               const float* __restrict__ xtr,
                                               const float* __restrict__ Wl1,
                                               const float* __restrict__ Wr1,
                                               const float* __restrict__ We1,
                                               const float* __restrict__ Wl2,
                                               const float* __restrict__ Wr2,
                                               const float* __restrict__ We2,
                                               const float* __restrict__ bl1,
                                               const float* __restrict__ br1,
                                               const float* __restrict__ be1,
                                               const float* __restrict__ bl2,
                                               const float* __restrict__ br2,
                                               const int* __restrict__ adj,
                                               int* __restrict__ cnt,
                                               int* __restrict__ inc,
                                               short* __restrict__ Xb,
                                               short* __restrict__ xtr_b,
                                               short* __restrict__ WT12,
                                               short* __restrict__ WTall,
                                               short* __restrict__ We2T,
                                               float* __restrict__ blr1,
                                               float* __restrict__ bfull,
                                               int NN, int NE) {
  size_t idx = (size_t)blockIdx.x * 256 + threadIdx.x;
  size_t n;
  n = (size_t)NN * 32;      // Xb concat, 8 bf16 per thread
  if (idx < n) {
    int row = (int)(idx >> 5), q = (int)(idx & 31);
    const float* src = (q < 16) ? &xn[(size_t)row * 128 + q * 8]
                                : &xlg[(size_t)row * 128 + (q - 16) * 8];
    *(short8*)&Xb[(size_t)row * 256 + q * 8] = cvt8(src);
    return;
  }
  idx -= n;
  n = (size_t)NE * 16;      // xtr_b: x_trace -> bf16, 8 per thread
  if (idx < n) {
    *(short8*)&xtr_b[idx * 8] = cvt8(&xtr[idx * 8]);
    return;
  }
  idx -= n;
  n = 512 * 256;            // WT12[n512][k256] from Wl1|Wr1
  if (idx < n) {
    int nn = (int)(idx >> 8), k = (int)(idx & 255);
    float v = (nn < 256) ? Wl1[(size_t)k * 256 + nn] : Wr1[(size_t)k * 256 + (nn - 256)];
    WT12[idx] = f2b(v);
    return;
  }
  idx -= n;
  n = 512 * 128;            // WTall[n512][k128] = We1T(256) | Wl2T(128) | Wr2T(128)
  if (idx < n) {
    int nn = (int)(idx >> 7), k = (int)(idx & 127);
    float v;
    if (nn < 256)      v = We1[(size_t)k * 256 + nn];
    else if (nn < 384) v = Wl2[(size_t)k * 128 + (nn - 256)];
    else               v = Wr2[(size_t)k * 128 + (nn - 384)];
    WTall[idx] = f2b(v);
    return;
  }
  idx -= n;
  n = 128 * 256;            // We2T[n128][k256]
  if (idx < n) {
    int nn = (int)(idx >> 8), k = (int)(idx & 255);
    We2T[idx] = f2b(We2[(size_t)k * 128 + nn]);
    return;
  }
  idx -= n;
  n = 512;                  // blr1 = bl1|br1
  if (idx < n) { blr1[idx] = (idx < 256) ? bl1[idx] : br1[idx - 256]; return; }
  idx -= n;
  n = 512;                  // bfull = be1|bl2|br2
  if (idx < n) {
    bfull[idx] = (idx < 256) ? be1[idx] : (idx < 384 ? bl2[idx - 256] : br2[idx - 384]);
    return;
  }
  idx -= n;
  n = (size_t)NE;           // inverse incidence (cnt pre-zeroed by memset)
  if (idx < n) {
    int dst = adj[NE + idx];
    int slot = atomicAdd(&cnt[dst], 1);
    inc[dst * KDEG + slot] = (int)idx;
  }
}

// ---- dual GEMM launch: blocks [0,640) do xlr1 = Xb@WT12 (M=NN,K=256,N=512);
// blocks [640,3840) do pool2 = xtr_b@[Wl2T|Wr2T] (M=NE,K=128,N=256).
// Both halves XCD-chunk swizzled: all n-blocks of one A-panel land on one
// XCD's L2 (A-panel fetched once per XCD instead of 8x/4x from L3).
__global__ __launch_bounds__(256) void k_gemm_dual(const short* __restrict__ Xb,
                                                   const short* __restrict__ WT12,
                                                   const float* __restrict__ blr1,
                                                   float* __restrict__ xlr1,
                                                   const short* __restrict__ xtr_b,
                                                   const short* __restrict__ WTl2,
                                                   const float* __restrict__ bia2,
                                                   float* __restrict__ pool2,
                                                   int NN, int NE) {
  __shared__ __align__(16) short As[64][40];
  __shared__ __align__(16) short Bs[64][40];
  const int tid = threadIdx.x;
  const int wave = tid >> 6, lane = tid & 63;
  const int quad = lane >> 4, l16 = lane & 15;
  const short *A, *WT;
  const float* bias;
  float* C;
  int K, N, m0, n0;
  {
    int bid = blockIdx.x;
    const int g1 = 8 * (NN / 64);          // 640
    if (bid < g1) {
      int l = (bid & 7) * (g1 >> 3) + (bid >> 3);
      A = Xb; WT = WT12; bias = blr1; C = xlr1; K = 256; N = 512;
      n0 = (l & 7) * 64; m0 = (l >> 3) * 64;
    } else {
      bid -= g1;
      const int g2 = 4 * (NE / 64);        // 3200
      int l = (bid & 7) * (g2 >> 3) + (bid >> 3);
      A = xtr_b; WT = WTl2; bias = bia2; C = pool2; K = 128; N = 256;
      n0 = (l & 3) * 64; m0 = (l >> 2) * 64;
    }
  }
  const int wm = (wave & 1) * 32, wn = (wave >> 1) * 32;
  const int r = tid >> 2, kc = (tid & 3) << 3;
  f32x4 acc[2][2] = {};
  short8 pa = *(const short8*)&A[(size_t)(m0 + r) * K + kc];
  short8 pb = *(const short8*)&WT[(size_t)(n0 + r) * K + kc];
  for (int k0 = 0; k0 < K; k0 += 32) {
    *(short8*)&As[r][kc] = pa;
    *(short8*)&Bs[r][kc] = pb;
    __syncthreads();
    if (k0 + 32 < K) {
      pa = *(const short8*)&A[(size_t)(m0 + r) * K + (k0 + 32 + kc)];
      pb = *(const short8*)&WT[(size_t)(n0 + r) * K + (k0 + 32 + kc)];
    }
    short8 af[2], bf[2];
    #pragma unroll
    for (int mt = 0; mt < 2; ++mt)
      af[mt] = *(const short8*)&As[wm + mt * 16 + l16][quad << 3];
    #pragma unroll
    for (int nt = 0; nt < 2; ++nt)
      bf[nt] = *(const short8*)&Bs[wn + nt * 16 + l16][quad << 3];
    #pragma unroll
    for (int mt = 0; mt < 2; ++mt)
      #pragma unroll
      for (int nt = 0; nt < 2; ++nt)
        acc[mt][nt] = __builtin_amdgcn_mfma_f32_16x16x32_bf16(
            af[mt], bf[nt], acc[mt][nt], 0, 0, 0);
    __syncthreads();
  }
  #pragma unroll
  for (int nt = 0; nt < 2; ++nt) {
    int col = n0 + wn + nt * 16 + l16;
    float bs = bias[col];
    #pragma unroll
    for (int mt = 0; mt < 2; ++mt) {
      int row = m0 + wm + mt * 16 + (quad << 2);
      #pragma unroll
      for (int rr = 0; rr < 4; ++rr)
        C[(size_t)(row + rr) * N + col] = acc[mt][nt][rr] + bs;
    }
  }
}

// ---- MFMA GEMM 64x64 tile, BK=64 (nproj only; K multiple of 64).
__global__ __launch_bounds__(256) void k_gemm_mfma64(const short* __restrict__ A,
                                                     const short* __restrict__ WT,
                                                     const float* __restrict__ bias,
                                                     float* __restrict__ C,
                                                     int M, int K, int N) {
  __shared__ __align__(16) short As[64][72];
  __shared__ __align__(16) short Bs[64][72];
  const int tid = threadIdx.x;
  const int wave = tid >> 6, lane = tid & 63;
  const int quad = lane >> 4, l16 = lane & 15;
  const int m0 = blockIdx.y * 64, n0 = blockIdx.x * 64;
  const int wm = (wave & 1) * 32, wn = (wave >> 1) * 32;
  const int r = tid >> 2, kc = (tid & 3) << 4;   // 16 bf16 per thread per mat
  f32x4 acc[2][2] = {};
  short8 pa0 = *(const short8*)&A[(size_t)(m0 + r) * K + kc];
  short8 pa1 = *(const short8*)&A[(size_t)(m0 + r) * K + kc + 8];
  short8 pb0 = *(const short8*)&WT[(size_t)(n0 + r) * K + kc];
  short8 pb1 = *(const short8*)&WT[(size_t)(n0 + r) * K + kc + 8];
  for (int k0 = 0; k0 < K; k0 += 64) {
    *(short8*)&As[r][kc] = pa0;
    *(short8*)&As[r][kc + 8] = pa1;
    *(short8*)&Bs[r][kc] = pb0;
    *(short8*)&Bs[r][kc + 8] = pb1;
    __syncthreads();
    if (k0 + 64 < K) {
      pa0 = *(const short8*)&A[(size_t)(m0 + r) * K + (k0 + 64 + kc)];
      pa1 = *(const short8*)&A[(size_t)(m0 + r) * K + (k0 + 64 + kc + 8)];
      pb0 = *(const short8*)&WT[(size_t)(n0 + r) * K + (k0 + 64 + kc)];
      pb1 = *(const short8*)&WT[(size_t)(n0 + r) * K + (k0 + 64 + kc + 8)];
    }
    #pragma unroll
    for (int kk = 0; kk < 2; ++kk) {
      short8 af[2], bf[2];
      #pragma unroll
      for (int mt = 0; mt < 2; ++mt)
        af[mt] = *(const short8*)&As[wm + mt * 16 + l16][kk * 32 + (quad << 3)];
      #pragma unroll
      for (int nt = 0; nt < 2; ++nt)
        bf[nt] = *(const short8*)&Bs[wn + nt * 16 + l16][kk * 32 + (quad << 3)];
      #pragma unroll
      for (int mt = 0; mt < 2; ++mt)
        #pragma unroll
        for (int nt = 0; nt < 2; ++nt)
          acc[mt][nt] = __builtin_amdgcn_mfma_f32_16x16x32_bf16(
              af[mt], bf[nt], acc[mt][nt], 0, 0, 0);
    }
    __syncthreads();
  }
  #pragma unroll
  for (int nt = 0; nt < 2; ++nt) {
    int col = n0 + wn + nt * 16 + l16;
    float bs = bias[col];
    #pragma unroll
    for (int mt = 0; mt < 2; ++mt) {
      int row = m0 + wm + mt * 16 + (quad << 2);
      #pragma unroll
      for (int rr = 0; rr < 4; ++rr)
        C[(size_t)(row + rr) * N + col] = acc[mt][nt][rr] + bs;
    }
  }
}

// ---- logit-GEMM, 128x64 tile = ONE HEAD per block (1600 uniform blocks).
__global__ __launch_bounds__(256) void k_logit(const short* __restrict__ A,
                                               const short* __restrict__ WT,
                                               const float* __restrict__ bfull,
                                               const float* __restrict__ att1,
                                               const int* __restrict__ adj,
                                               const float* __restrict__ xlr1,
                                               float* __restrict__ logit1,
                                               int NE) {
  const int K = 128;
  struct SmemGemm { short As[128][40]; short Bs[64][40]; };
  struct SmemEpi  { int sdst[128]; float sxl[14][68]; float sxr[NPG][68]; };
  __shared__ __align__(16) union { SmemGemm g; SmemEpi e; } sm;
  const int tid = threadIdx.x;
  const int wave = tid >> 6, lane = tid & 63;
  const int quad = lane >> 4, l16 = lane & 15;
  int bid = blockIdx.x;
  int l = (bid & 7) * ((int)gridDim.x >> 3) + (bid >> 3);
  const int n0 = (l & 3) << 6;       // 0,64,128,192 -> head = n0>>6
  const int m0 = (l >> 2) << 7;      // edge panel (128 edges)
  const int wm = wave * 32;          // wave covers 32 rows x 64 cols
  const int ra0 = tid >> 2, ra1 = ra0 + 64;   // A rows (2 per thread); B row = ra0
  const int kc = (tid & 3) << 3;
  f32x4 acc[2][4] = {};
  short8 pa0 = *(const short8*)&A[(size_t)(m0 + ra0) * K + kc];
  short8 pa1 = *(const short8*)&A[(size_t)(m0 + ra1) * K + kc];
  short8 pb  = *(const short8*)&WT[(size_t)(n0 + ra0) * K + kc];
  for (int k0 = 0; k0 < K; k0 += 32) {
    *(short8*)&sm.g.As[ra0][kc] = pa0;
    *(short8*)&sm.g.As[ra1][kc] = pa1;
    *(short8*)&sm.g.Bs[ra0][kc] = pb;
    __syncthreads();
    if (k0 + 32 < K) {
      pa0 = *(const short8*)&A[(size_t)(m0 + ra0) * K + (k0 + 32 + kc)];
      pa1 = *(const short8*)&A[(size_t)(m0 + ra1) * K + (k0 + 32 + kc)];
      pb  = *(const short8*)&WT[(size_t)(n0 + ra0) * K + (k0 + 32 + kc)];
    }
    short8 af[2], bf[4];
    #pragma unroll
    for (int mt = 0; mt < 2; ++mt)
      af[mt] = *(const short8*)&sm.g.As[wm + mt * 16 + l16][quad << 3];
    #pragma unroll
    for (int nt = 0; nt < 4; ++nt)
      bf[nt] = *(const short8*)&sm.g.Bs[nt * 16 + l16][quad << 3];
    #pragma unroll
    for (int mt = 0; mt < 2; ++mt)
      #pragma unroll
      for (int nt = 0; nt < 4; ++nt)
        acc[mt][nt] = __builtin_amdgcn_mfma_f32_16x16x32_bf16(
            af[mt], bf[nt], acc[mt][nt], 0, 0, 0);
    __syncthreads();
  }
  // ---- fused layer-1 logit epilogue: per-graph xr staging (40 rows x 64 cols)
  const int gl = m0 / EPG;
  const int gh = (m0 + 127) / EPG;
  const int slo = m0 / KDEG;
  const int nrl = (m0 + 127) / KDEG - slo + 1;  // 13 or 14 xl rows
  if (tid < 128) sm.e.sdst[tid] = adj[NE + m0 + tid];
  for (int s = tid; s < nrl * 64; s += 256) {
    int row = s >> 6, c = s & 63;
    sm.e.sxl[row][c] = xlr1[(size_t)(slo + row) * 512 + n0 + c];
  }
  const int h = n0 >> 6;
  float attv[4], bev[4];
  int ccl[4];
  #pragma unroll
  for (int nt = 0; nt < 4; ++nt) {
    int col = n0 + nt * 16 + l16;
    ccl[nt] = col - n0;
    attv[nt] = att1[col] * LOG2E;
    bev[nt] = bfull[col];
  }
  for (int g = gl; g <= gh; ++g) {
    __syncthreads();   // order vs sxl writes (g=gl) / prior reads (g>gl)
    for (int s = tid; s < NPG * 64; s += 256) {
      int row = s >> 6, c = s & 63;
      sm.e.sxr[row][c] = xlr1[(size_t)(g * NPG + row) * 512 + 256 + n0 + c];
    }
    __syncthreads();
    const int elo = g * EPG, ehi = elo + EPG;
    #pragma unroll
    for (int mt = 0; mt < 2; ++mt) {
      #pragma unroll
      for (int r = 0; r < 4; ++r) {
        int le = wm + mt * 16 + (quad << 2) + r;   // 0..127
        int e = m0 + le;
        if (e < elo || e >= ehi) continue;   // uniform across each 16-lane grp
        int srow = e / KDEG - slo;
        int d = sm.e.sdst[le];
        int drow = d - g * NPG;
        float p = 0.f;
        #pragma unroll
        for (int nt = 0; nt < 4; ++nt) {
          float v = acc[mt][nt][r] + bev[nt] + sm.e.sxl[srow][ccl[nt]]
                  + sm.e.sxr[drow][ccl[nt]];
          v = (v > 0.f) ? v : 0.2f * v;
          p += v * attv[nt];
        }
        p += __shfl_xor(p, 1, 64);
        p += __shfl_xor(p, 2, 64);
        p += __shfl_xor(p, 4, 64);
        p += __shfl_xor(p, 8, 64);
        if (l16 == 0) {
          logit1[(size_t)e * 4 + h] = exp2f(p);
        }
      }
    }
  }
}

// ---- layer1 aggregate (gather) + in-block den + fused fp32 output writes.
// XCD-chunked block->node swizzle (T1): sliding 10-row xlr1 window stays
// L2-resident within each XCD's contiguous node range.
__global__ __launch_bounds__(256) void k_agg1(const int* __restrict__ adj,
                                              const int* __restrict__ inc,
                                              const float* __restrict__ xlr1,
                                              const float* __restrict__ logit1,
                                              const float* __restrict__ bias1,
                                              short* __restrict__ nodeoutb,
                                              float* __restrict__ out_node,
                                              float* __restrict__ out_log) {
  int u = (blockIdx.x & 7) * ((int)gridDim.x >> 3) + (blockIdx.x >> 3);
  int c = threadIdx.x;
  __shared__ int se[KDEG], ssrc[KDEG];
  __shared__ float slg[KDEG * 4];
  if (c < KDEG) se[c] = inc[u * KDEG + c];
  __syncthreads();
  if (c < KDEG) ssrc[c] = adj[se[c]];
  else if (c >= 64 && c < 64 + KDEG * 4) {
    int t = c - 64;
    slg[t] = logit1[(size_t)se[t >> 2] * 4 + (t & 3)];
  }
  __syncthreads();
  int h = c >> 6;
  float den = 0.f;
  #pragma unroll
  for (int j = 0; j < KDEG; ++j) den += slg[j * 4 + h];
  float rden = 1.f / (den + 1e-16f);
  float acc = 0.f;
  #pragma unroll
  for (int j = 0; j < KDEG; ++j)
    acc += slg[j * 4 + h] * xlr1[(size_t)ssrc[j] * 512 + c];
  float val = acc * rden + bias1[c];
  nodeoutb[(size_t)u * D1 + c] = f2b(val);
  if (c < 128) out_node[(size_t)u * 128 + c] = val;
  else         out_log[(size_t)u * 128 + (c - 128)] = val;
}

// ---- layer2 gather: one block per 100-line-edge group (node).
// Reads xl2|xr2 from pool2 [NE,256]; writes final out_trace (single write).
// XCD-chunked gi swizzle (T1): consecutive nodes' ein windows overlap and
// eout rows are contiguous -> pool2 sliding window L2-resident per XCD.
__global__ __launch_bounds__(256) void k_gat2_v4(const int* __restrict__ eadj,
                                                 const int* __restrict__ efea,
                                                 const float* __restrict__ pool2,
                                                 const float* __restrict__ nproj,
                                                 const float* __restrict__ att2,
                                                 const float* __restrict__ bias2,
                                                 float* __restrict__ out_trace,
                                                 int NL) {
  int gi = (blockIdx.x & 7) * ((int)gridDim.x >> 3) + (blockIdx.x >> 3);
  size_t le0 = (size_t)gi * 100;
  int t = threadIdx.x;
  const int wave = t >> 6, lane = t & 63;
  __shared__ int ein[KDEG], eout[KDEG], nvs;
  __shared__ float xs[KDEG][132];    // xl2 rows (pad 132: conflict-spread)
  __shared__ float rs[KDEG][132];    // xr2 rows + nproj
  __shared__ float as_[DE];          // att2 * log2e
  __shared__ float exs[400];         // ex[(j*10+o)*4+h]
  __shared__ float rdn[40];          // 1/den [o*4+h]
  if (t < KDEG)          ein[t] = eadj[le0 + (size_t)t * KDEG];
  else if (t < 2 * KDEG) eout[t - KDEG] = eadj[(size_t)NL + le0 + (t - KDEG)];
  else if (t == 255)     nvs = efea[le0];
  __syncthreads();
  int nv = nvs;
  for (int s = t; s < 320; s += 256) {
    int j = s >> 5, q = (s & 31) << 2;
    *(float4*)&xs[j][q] = *(const float4*)&pool2[(size_t)ein[j] * 256 + q];
    float4 tr4 = *(const float4*)&pool2[(size_t)eout[j] * 256 + 128 + q];
    float4 ea4 = *(const float4*)&nproj[(size_t)nv * DE + q];
    float4 r;
    r.x = tr4.x + ea4.x; r.y = tr4.y + ea4.y;
    r.z = tr4.z + ea4.z; r.w = tr4.w + ea4.w;
    *(float4*)&rs[j][q] = r;
  }
  if (t < 32) {
    float4 a4 = *(const float4*)&att2[t << 2];
    float4 o;
    o.x = a4.x * LOG2E; o.y = a4.y * LOG2E;
    o.z = a4.z * LOG2E; o.w = a4.w * LOG2E;
    *(float4*)&as_[t << 2] = o;
  }
  __syncthreads();
  // Phase A: 400 logits; wave w handles head w; lane sweeps (j,o) pairs.
  {
    int h = wave;
    const float* aa = &as_[h << 5];
    for (int idx = lane; idx < 100; idx += 64) {
      int j = idx / 10;
      int o = idx - j * 10;
      const float* xa = &xs[j][h << 5];
      const float* ra = &rs[o][h << 5];
      float p = 0.f;
      #pragma unroll
      for (int i = 0; i < 32; i += 4) {
        float4 xv = *(const float4*)&xa[i];
        float4 rv = *(const float4*)&ra[i];
        float4 av = *(const float4*)&aa[i];
        float v;
        v = xv.x + rv.x; v = (v > 0.f) ? v : 0.2f * v; p += v * av.x;
        v = xv.y + rv.y; v = (v > 0.f) ? v : 0.2f * v; p += v * av.y;
        v = xv.z + rv.z; v = (v > 0.f) ? v : 0.2f * v; p += v * av.z;
        v = xv.w + rv.w; v = (v > 0.f) ? v : 0.2f * v; p += v * av.w;
      }
      exs[(j * 10 + o) * 4 + h] = exp2f(p);
    }
  }
  __syncthreads();
  if (t < 40) {       // 1/den per (o,h): h=t&3, o=t>>2
    float d = 0.f;
    #pragma unroll
    for (int j = 0; j < KDEG; ++j) d += exs[(j * 10 + (t >> 2)) * 4 + (t & 3)];
    rdn[t] = 1.f / d;
  }
  __syncthreads();
  // Phase B: out[o][c] = (sum_j ex[j,o,h] * xl[j][c]) * rden[o,h] + bias[c]
  {
    int c = t & 127, h = c >> 5, oh = (t >> 7) * 5;
    float bsv = bias2[c];
    #pragma unroll
    for (int oo = 0; oo < 5; ++oo) {
      int o = oh + oo;
      float acc = 0.f;
      #pragma unroll
      for (int j = 0; j < KDEG; ++j)
        acc += exs[(j * 10 + o) * 4 + h] * xs[j][c];
      out_trace[(size_t)eout[o] * DE + c] = acc * rdn[o * 4 + h] + bsv;
    }
  }
}

extern "C" void kernel_launch(void* const* d_in, const int* in_sizes, int n_in,
                              void* d_out, int out_size, void* d_ws, size_t ws_size,
                              hipStream_t stream) {
  const float* x_node   = (const float*)d_in[0];
  const float* x_trace  = (const float*)d_in[1];
  const float* x_log    = (const float*)d_in[2];
  const int*   node_adj = (const int*)d_in[3];
  const int*   edge_adj = (const int*)d_in[4];
  const int*   edge_efea= (const int*)d_in[5];
  const float* Wl1 = (const float*)d_in[6];
  const float* bl1 = (const float*)d_in[7];
  const float* Wr1 = (const float*)d_in[8];
  const float* br1 = (const float*)d_in[9];
  const float* We1 = (const float*)d_in[10];
  const float* be1 = (const float*)d_in[11];
  const float* att1 = (const float*)d_in[12];
  const float* bias1 = (const float*)d_in[13];
  const float* Wl2 = (const float*)d_in[14];
  const float* bl2 = (const float*)d_in[15];
  const float* Wr2 = (const float*)d_in[16];
  const float* br2 = (const float*)d_in[17];
  const float* We2 = (const float*)d_in[18];
  const float* be2 = (const float*)d_in[19];
  const float* att2 = (const float*)d_in[20];
  const float* bias2 = (const float*)d_in[21];

  const int NN = in_sizes[0] / 128;   // 5120 nodes
  const int NE = in_sizes[1] / 128;   // 51200 edges
  const int NL = in_sizes[5];         // 512000 line edges

  // ---- workspace layout
  char* p = (char*)d_ws;
  float* pool2   = (float*)p; p += al256((size_t)NE * 256 * 4);   // xl2|xr2
  float* xlr1    = (float*)p; p += al256((size_t)NN * 512 * 4);
  short* Xb      = (short*)p; p += al256((size_t)NN * D1 * 2);
  short* xtr_b   = (short*)p; p += al256((size_t)NE * DE * 2);
  short* nodeoutb= (short*)p; p += al256((size_t)NN * D1 * 2);
  float* nproj   = (float*)p; p += al256((size_t)NN * DE * 4);
  float* logit1  = (float*)p; p += al256((size_t)NE * 4 * 4);
  int*   inc     = (int*)p;   p += al256((size_t)NN * KDEG * 4);
  int*   cnt     = (int*)p;   p += al256((size_t)NN * 4);
  short* WT12    = (short*)p; p += al256((size_t)512 * 256 * 2);
  short* WTall   = (short*)p; p += al256((size_t)512 * 128 * 2);
  short* We2T    = (short*)p; p += al256((size_t)128 * 256 * 2);
  float* blr1    = (float*)p; p += al256(512 * 4);
  float* bfull   = (float*)p; p += al256(512 * 4);
  (void)ws_size;

  float* out_node  = (float*)d_out;
  float* out_trace = out_node + (size_t)NN * 128;
  float* out_log   = out_trace + (size_t)NE * 128;

  // ---- zero slot counters, then setup (+incidence) in one launch
  hipMemsetAsync(cnt, 0, (size_t)NN * 4, stream);
  {
    size_t total = (size_t)NN * 32 + (size_t)NE * 16 +
                   512 * 256 + 512 * 128 + 128 * 256 + 512 + 512 + (size_t)NE;
    k_setup<<<cdiv(total, 256), 256, 0, stream>>>(x_node, x_log, x_trace,
                                                  Wl1, Wr1, We1, Wl2, Wr2, We2,
                                                  bl1, br1, be1, bl2, br2,
                                                  node_adj, cnt, inc,
                                                  Xb, xtr_b,
                                                  WT12, WTall, We2T, blr1, bfull,
                                                  NN, NE);
  }

  // ---- dual GEMM: xlr1 (640 blocks) + pool2 streamer (3200 blocks)
  k_gemm_dual<<<8 * (NN / 64) + 4 * (NE / 64), 256, 0, stream>>>(
      Xb, WT12, blr1, xlr1,
      xtr_b, WTall + (size_t)256 * 128, bfull + 256, pool2, NN, NE);

  // ---- layer-1 logits: one head per block, 1600 uniform blocks
  k_logit<<<4 * (NE / 128), 256, 0, stream>>>(xtr_b, WTall, bfull, att1,
                                              node_adj, xlr1, logit1, NE);

  // ---- layer 1 aggregate (XCD-swizzled; writes nodeoutb + node/log outputs)
  k_agg1<<<NN, 256, 0, stream>>>(node_adj, inc, xlr1, logit1, bias1,
                                 nodeoutb, out_node, out_log);

  // ---- layer 2: node projection GEMM (BK=64)
  k_gemm_mfma64<<<dim3(DE / 64, NN / 64), 256, 0, stream>>>(nodeoutb, We2T, be2,
                                                            nproj, NN, D1, DE);

  // ---- layer 2: fused gather/softmax/aggregate (XCD-swizzled)
  k_gat2_v4<<<NN, 256, 0, stream>>>(edge_adj, edge_efea, pool2, nproj,
                                    att2, bias2, out_trace, NL);
}